// Round 9
// baseline (721.363 us; speedup 1.0000x reference)
//
#include <hip/hip_runtime.h>

#define NN 50000
#define NE 800000
#define NG 64
#define HID 128

typedef __attribute__((ext_vector_type(8))) short bf16x8;
typedef __attribute__((ext_vector_type(4))) float f32x4;

// bf16 helpers (RNE)
__device__ __forceinline__ unsigned short f2b(float f) {
  unsigned u = __float_as_uint(f);
  u += 0x7fffu + ((u >> 16) & 1u);
  return (unsigned short)(u >> 16);
}
__device__ __forceinline__ float b2f(unsigned short b) {
  return __uint_as_float(((unsigned)b) << 16);
}

// ---------------------------------------------------------------- CSR build
__global__ void count_edges(const int* __restrict__ ei, int* __restrict__ cnt_dst,
                            int* __restrict__ cnt_src) {
  int e = blockIdx.x * 256 + threadIdx.x;
  if (e >= NE) return;
  atomicAdd(&cnt_src[ei[e]], 1);
  atomicAdd(&cnt_dst[ei[NE + e]], 1);
}

__global__ void scanA_dis(const int* __restrict__ cnt, int* __restrict__ partial,
                          float* __restrict__ dis) {
  __shared__ int s[256];
  int t = threadIdx.x;
  int i = blockIdx.x * 256 + t;
  int v = (i < NN) ? cnt[i] : 0;
  if (i < NN) dis[i] = rsqrtf((float)(v + 1));  // +1 self loop
  s[t] = v;
  __syncthreads();
  for (int off = 128; off; off >>= 1) {
    if (t < off) s[t] += s[t + off];
    __syncthreads();
  }
  if (!t) partial[blockIdx.x] = s[0];
}

__global__ void scanB_bounds(int* __restrict__ partial, int nb,
                             const int* __restrict__ batch, int* __restrict__ gstart) {
  int t = threadIdx.x;
  if (t == 0) {
    int acc = 0;
    for (int i = 0; i < nb; ++i) { int v = partial[i]; partial[i] = acc; acc += v; }
  }
  if (t >= 1 && t <= NG + 1) {
    int g = t - 1;
    int lo = 0, hi = NN;
    while (lo < hi) { int mid = (lo + hi) >> 1; if (batch[mid] < g) lo = mid + 1; else hi = mid; }
    gstart[g] = lo;
  }
}

__global__ void scanC(const int* __restrict__ cnt, const int* __restrict__ partial,
                      int* __restrict__ rowptr) {
  __shared__ int bufA[256], bufB[256];
  int t = threadIdx.x;
  int i = blockIdx.x * 256 + t;
  int v = (i < NN) ? cnt[i] : 0;
  bufA[t] = v;
  __syncthreads();
  int* src = bufA; int* dst = bufB;
  for (int off = 1; off < 256; off <<= 1) {
    int x = src[t];
    if (t >= off) x += src[t - off];
    dst[t] = x;
    __syncthreads();
    int* tmp = src; src = dst; dst = tmp;
  }
  int incl = src[t];
  if (i < NN) rowptr[i] = partial[blockIdx.x] + incl - v;
  if (i == NN - 1) rowptr[NN] = partial[blockIdx.x] + incl;
}

__global__ void fill_edges(const int* __restrict__ ei, const int* __restrict__ rowptr,
                           int* __restrict__ fillpos, int* __restrict__ col) {
  int e = blockIdx.x * 256 + threadIdx.x;
  if (e >= NE) return;
  int s = ei[e], d = ei[NE + e];
  int p = atomicAdd(&fillpos[d], 1);
  col[rowptr[d] + p] = s;
}

// ---------------------------------------------------------------- fragment pack (all matrices)
__global__ void prep_all(const float* __restrict__ gcn_W, const float* __restrict__ gat_W,
                         const float* __restrict__ hW1, const float* __restrict__ aW1,
                         const float* __restrict__ projW, unsigned short* __restrict__ wfrag,
                         unsigned short* __restrict__ nfrag, unsigned short* __restrict__ pfrag) {
  int m = blockIdx.y;
  int idx = blockIdx.x * 256 + threadIdx.x;  // 0..16383
  int j = idx & 7, lane = (idx >> 3) & 63, t = idx >> 9;
  int ct = t >> 2, ks = t & 3;
  int k = ks * 32 + ((lane >> 4) << 3) + j;
  int c = (ct << 4) + (lane & 15);
  if (m < 3) {
    wfrag[(size_t)m * 32768 + idx] = f2b(gcn_W[(size_t)m * 16384 + k * 128 + c]);
    wfrag[(size_t)m * 32768 + 16384 + idx] = f2b(gat_W[(size_t)m * 16384 + k * 128 + c]);
  } else if (m == 3) {
    float v = (c < 64) ? hW1[k * 64 + c] : aW1[k * 64 + (c - 64)];
    nfrag[idx] = f2b(v);
  } else {
    pfrag[idx] = f2b(projW[k * 128 + c]);
  }
}

// ---------------------------------------------------------------- A-fragment loaders
__device__ __forceinline__ void load_a_frags_f32(const float* __restrict__ xp, int lane,
                                                 bf16x8 a[4]) {
#pragma unroll
  for (int ks = 0; ks < 4; ++ks) {
    int k0 = ks * 32 + ((lane >> 4) << 3);
    float4 u = *(const float4*)&xp[k0];
    float4 v = *(const float4*)&xp[k0 + 4];
    bf16x8 t;
    t[0] = (short)f2b(u.x); t[1] = (short)f2b(u.y); t[2] = (short)f2b(u.z); t[3] = (short)f2b(u.w);
    t[4] = (short)f2b(v.x); t[5] = (short)f2b(v.y); t[6] = (short)f2b(v.z); t[7] = (short)f2b(v.w);
    a[ks] = t;
  }
}

__device__ __forceinline__ void load_a_frags_b16(const unsigned short* __restrict__ xp,
                                                 int lane, bf16x8 a[4]) {
#pragma unroll
  for (int ks = 0; ks < 4; ++ks) {
    int k0 = ks * 32 + ((lane >> 4) << 3);
    a[ks] = *(const bf16x8*)&xp[k0];
  }
}

// ---------------------------------------------------------------- projection MFMA GEMM -> bf16 xb
__global__ __launch_bounds__(256) void gemm_proj_mfma(
    const float* __restrict__ X, const unsigned short* __restrict__ F,
    const float* __restrict__ bias, unsigned short* __restrict__ XB, int nrows) {
  __shared__ unsigned short Ys[64 * 128];  // 16 KB
  int tid = threadIdx.x;
  int w = tid >> 6, lane = tid & 63;
  int row0 = blockIdx.x * 64;
  int row = row0 + w * 16 + (lane & 15);
  const float* xp = (row < nrows) ? &X[(size_t)row * 128] : &X[0];
  bf16x8 a[4];
  load_a_frags_f32(xp, lane, a);
  f32x4 acc[8];
#pragma unroll
  for (int ct = 0; ct < 8; ++ct) acc[ct] = (f32x4){0.f, 0.f, 0.f, 0.f};
#pragma unroll
  for (int ct = 0; ct < 8; ++ct) {
#pragma unroll
    for (int ks = 0; ks < 4; ++ks) {
      bf16x8 b = *(const bf16x8*)&F[((ct * 4 + ks) * 64 + lane) * 8];
      acc[ct] = __builtin_amdgcn_mfma_f32_16x16x32_bf16(a[ks], b, acc[ct], 0, 0, 0);
    }
  }
#pragma unroll
  for (int ct = 0; ct < 8; ++ct) {
    int c = (ct << 4) + (lane & 15);
    float bv = bias[c];
#pragma unroll
    for (int j = 0; j < 4; ++j) {
      int r = w * 16 + ((lane >> 4) << 2) + j;
      Ys[r * 128 + c] = f2b(acc[ct][j] + bv);
    }
  }
  __syncthreads();
  int nr = min(nrows - row0, 64);
  const uint4* ys4 = (const uint4*)Ys;
  uint4* y4 = (uint4*)(XB + (size_t)row0 * 128);
  for (int e = tid; e < nr * 16; e += 256) y4[e] = ys4[e];
}

// ---------------------------------------------------------------- dual MFMA GEMM -> G + fused GAT scores
// block 0 zeroes S1/S2 for the following edge_aggregate's fused stats.
__global__ __launch_bounds__(256) void gemm_dual_mfma(
    const unsigned short* __restrict__ XB, const unsigned short* __restrict__ F1,
    const unsigned short* __restrict__ F2, const float* __restrict__ asrc,
    const float* __restrict__ adst, const float* __restrict__ dis,
    unsigned short* __restrict__ G, float* __restrict__ a_s, float* __restrict__ a_d,
    float* __restrict__ S1z, int nrows) {
  if (blockIdx.x == 0) {
    for (int i = threadIdx.x; i < 2 * NG * 128; i += 256) S1z[i] = 0.f;
  }
  __shared__ unsigned short Gs[64 * 256];  // 32 KB
  int tid = threadIdx.x;
  int w = tid >> 6, lane = tid & 63;
  int row0 = blockIdx.x * 64;
  int row = row0 + w * 16 + (lane & 15);
  const unsigned short* xp = (row < nrows) ? &XB[(size_t)row * 128] : &XB[0];
  bf16x8 a[4];
  load_a_frags_b16(xp, lane, a);
  f32x4 acc1[8], acc2[8];
#pragma unroll
  for (int ct = 0; ct < 8; ++ct) {
    acc1[ct] = (f32x4){0.f, 0.f, 0.f, 0.f};
    acc2[ct] = (f32x4){0.f, 0.f, 0.f, 0.f};
  }
#pragma unroll
  for (int ct = 0; ct < 8; ++ct) {
#pragma unroll
    for (int ks = 0; ks < 4; ++ks) {
      int off = ((ct * 4 + ks) * 64 + lane) * 8;
      bf16x8 b1 = *(const bf16x8*)&F1[off];
      bf16x8 b2 = *(const bf16x8*)&F2[off];
      acc1[ct] = __builtin_amdgcn_mfma_f32_16x16x32_bf16(a[ks], b1, acc1[ct], 0, 0, 0);
      acc2[ct] = __builtin_amdgcn_mfma_f32_16x16x32_bf16(a[ks], b2, acc2[ct], 0, 0, 0);
    }
  }
  float dv[4];
#pragma unroll
  for (int j = 0; j < 4; ++j) {
    int gr = row0 + w * 16 + ((lane >> 4) << 2) + j;
    dv[j] = dis[gr < nrows ? gr : 0];
  }
#pragma unroll
  for (int ct = 0; ct < 8; ++ct) {
#pragma unroll
    for (int j = 0; j < 4; ++j) {
      int r = w * 16 + ((lane >> 4) << 2) + j;
      int c = (ct << 4) + (lane & 15);
      Gs[r * 256 + c] = f2b(acc1[ct][j] * dv[j]);
      Gs[r * 256 + 128 + c] = f2b(acc2[ct][j]);
    }
  }
  __syncthreads();
  int nr = min(nrows - row0, 64);
  const uint4* gs4 = (const uint4*)Gs;
  uint4* g4 = (uint4*)(G + (size_t)row0 * 256);
  for (int e = tid; e < nr * 32; e += 256) g4[e] = gs4[e];
  // fused attention scores from the LDS tile
  int f = 2 * lane;
  float as0 = asrc[f], as1 = asrc[f + 1];
  float ad0 = adst[f], ad1 = adst[f + 1];
  for (int i = 0; i < 16; ++i) {
    int r = w * 16 + i;
    int n = row0 + r;
    if (n >= nrows) break;
    ushort2 v = *(const ushort2*)&Gs[r * 256 + 128 + f];
    float x0 = b2f(v.x), x1 = b2f(v.y);
    float ps = x0 * as0 + x1 * as1;
    float pd = x0 * ad0 + x1 * ad1;
    ps += __shfl_xor(ps, 1); pd += __shfl_xor(pd, 1);
    ps += __shfl_xor(ps, 2); pd += __shfl_xor(pd, 2);
    ps += __shfl_xor(ps, 4); pd += __shfl_xor(pd, 4);
    ps += __shfl_xor(ps, 8); pd += __shfl_xor(pd, 8);
    if ((lane & 15) == 0) {
      int h = lane >> 4;
      a_s[n * 4 + h] = ps;
      a_d[n * 4 + h] = pd;
    }
  }
}

// ---------------------------------------------------------------- edge aggregation + fused GraphNorm stats
__device__ __forceinline__ float lrelu(float v) { return v > 0.f ? v : 0.2f * v; }

__global__ __launch_bounds__(256) void edge_aggregate_p(
    const unsigned short* __restrict__ G, const float* __restrict__ a_s,
    const float* __restrict__ a_d, const float* __restrict__ dis,
    const int* __restrict__ rowptr, const int* __restrict__ col,
    const int* __restrict__ batch, const float* __restrict__ gcn_b,
    const float* __restrict__ gat_b, float* __restrict__ hout,
    float* __restrict__ S1, float* __restrict__ S2) {
  __shared__ float S1loc[128], S2loc[128];
  int tid = threadIdx.x;
  if (tid < 128) { S1loc[tid] = 0.f; S2loc[tid] = 0.f; }
  int n = blockIdx.x * 4 + (tid >> 6);
  int lane = tid & 63;
  int es = lane >> 4, fl = lane & 15;
  int h = fl >> 2;
  int f8 = fl << 3;
  int p0 = rowptr[n], p1 = rowptr[n + 1];
  int cnt = p1 - p0 + 1;  // + self loop
  float adh = a_d[n * 4 + h];
  float dn = dis[n];
  float ag[8] = {0.f, 0.f, 0.f, 0.f, 0.f, 0.f, 0.f, 0.f};
  float aa[8] = {0.f, 0.f, 0.f, 0.f, 0.f, 0.f, 0.f, 0.f};
  float ssum = 0.f;
#define EDGE_ACC(eu, xv, hv)                                \
  do {                                                      \
    ag[0] += __uint_as_float((xv).x << 16);                 \
    ag[1] += __uint_as_float((xv).x & 0xffff0000u);         \
    ag[2] += __uint_as_float((xv).y << 16);                 \
    ag[3] += __uint_as_float((xv).y & 0xffff0000u);         \
    ag[4] += __uint_as_float((xv).z << 16);                 \
    ag[5] += __uint_as_float((xv).z & 0xffff0000u);         \
    ag[6] += __uint_as_float((xv).w << 16);                 \
    ag[7] += __uint_as_float((xv).w & 0xffff0000u);         \
    aa[0] += (eu)*__uint_as_float((hv).x << 16);            \
    aa[1] += (eu)*__uint_as_float((hv).x & 0xffff0000u);    \
    aa[2] += (eu)*__uint_as_float((hv).y << 16);            \
    aa[3] += (eu)*__uint_as_float((hv).y & 0xffff0000u);    \
    aa[4] += (eu)*__uint_as_float((hv).z << 16);            \
    aa[5] += (eu)*__uint_as_float((hv).z & 0xffff0000u);    \
    aa[6] += (eu)*__uint_as_float((hv).w << 16);            \
    aa[7] += (eu)*__uint_as_float((hv).w & 0xffff0000u);    \
  } while (0)
  int e = es;
  for (; e + 4 < cnt; e += 8) {
    int eB = e + 4;
    int srcA = (e < cnt - 1) ? col[p0 + e] : n;
    int srcB = (eB < cnt - 1) ? col[p0 + eB] : n;
    float euA = __expf(lrelu(a_s[srcA * 4 + h] + adh));
    float euB = __expf(lrelu(a_s[srcB * 4 + h] + adh));
    uint4 xvA = *(const uint4*)&G[(size_t)srcA * 256 + f8];
    uint4 hvA = *(const uint4*)&G[(size_t)srcA * 256 + 128 + f8];
    uint4 xvB = *(const uint4*)&G[(size_t)srcB * 256 + f8];
    uint4 hvB = *(const uint4*)&G[(size_t)srcB * 256 + 128 + f8];
    ssum += euA + euB;
    EDGE_ACC(euA, xvA, hvA);
    EDGE_ACC(euB, xvB, hvB);
  }
  for (; e < cnt; e += 4) {
    int src = (e < cnt - 1) ? col[p0 + e] : n;
    float eu = __expf(lrelu(a_s[src * 4 + h] + adh));
    uint4 xv = *(const uint4*)&G[(size_t)src * 256 + f8];
    uint4 hv = *(const uint4*)&G[(size_t)src * 256 + 128 + f8];
    ssum += eu;
    EDGE_ACC(eu, xv, hv);
  }
#undef EDGE_ACC
#pragma unroll
  for (int j = 0; j < 8; ++j) {
    ag[j] += __shfl_xor(ag[j], 16); ag[j] += __shfl_xor(ag[j], 32);
    aa[j] += __shfl_xor(aa[j], 16); aa[j] += __shfl_xor(aa[j], 32);
  }
  ssum += __shfl_xor(ssum, 16); ssum += __shfl_xor(ssum, 32);
  int g0 = batch[blockIdx.x * 4];
  bool fast = (batch[blockIdx.x * 4 + 3] == g0);
  __syncthreads();  // S1loc/S2loc zero-init visible to all warps
  if (es == 0) {
    float rs = 1.f / ssum;
    float4 gb0 = *(const float4*)&gcn_b[f8];
    float4 gb1 = *(const float4*)&gcn_b[f8 + 4];
    float4 tb0 = *(const float4*)&gat_b[f8];
    float4 tb1 = *(const float4*)&gat_b[f8 + 4];
    float o[8];
    o[0] = ag[0] * dn + aa[0] * rs + gb0.x + tb0.x;
    o[1] = ag[1] * dn + aa[1] * rs + gb0.y + tb0.y;
    o[2] = ag[2] * dn + aa[2] * rs + gb0.z + tb0.z;
    o[3] = ag[3] * dn + aa[3] * rs + gb0.w + tb0.w;
    o[4] = ag[4] * dn + aa[4] * rs + gb1.x + tb1.x;
    o[5] = ag[5] * dn + aa[5] * rs + gb1.y + tb1.y;
    o[6] = ag[6] * dn + aa[6] * rs + gb1.z + tb1.z;
    o[7] = ag[7] * dn + aa[7] * rs + gb1.w + tb1.w;
    float4 o0, o1;
    o0.x = o[0]; o0.y = o[1]; o0.z = o[2]; o0.w = o[3];
    o1.x = o[4]; o1.y = o[5]; o1.z = o[6]; o1.w = o[7];
    *(float4*)&hout[n * 128 + f8] = o0;
    *(float4*)&hout[n * 128 + f8 + 4] = o1;
    if (fast) {
#pragma unroll
      for (int j = 0; j < 8; ++j) {
        atomicAdd(&S1loc[f8 + j], o[j]);
        atomicAdd(&S2loc[f8 + j], o[j] * o[j]);
      }
    } else {
      int g = batch[n];
#pragma unroll
      for (int j = 0; j < 8; ++j) {
        atomicAdd(&S1[g * 128 + f8 + j], o[j]);
        atomicAdd(&S2[g * 128 + f8 + j], o[j] * o[j]);
      }
    }
  }
  __syncthreads();
  if (fast && tid < 128) {
    atomicAdd(&S1[g0 * 128 + tid], S1loc[tid]);
    atomicAdd(&S2[g0 * 128 + tid], S2loc[tid]);
  }
}

// ---------------------------------------------------------------- GraphNorm apply (bf16 x)
__global__ __launch_bounds__(256) void graph_norm(
    const float* __restrict__ h, const int* __restrict__ batch,
    const int* __restrict__ gstart, const float* __restrict__ S1,
    const float* __restrict__ S2, const float* __restrict__ nw,
    const float* __restrict__ nb, const float* __restrict__ nms,
    unsigned short* __restrict__ xb, int layer) {
  int idx = blockIdx.x * 256 + threadIdx.x;  // one float4 per thread
  if (idx >= NN * 32) return;
  int n = idx >> 5, fq = (idx & 31) << 2;
  int g = batch[n];
  float c = fmaxf((float)(gstart[g + 1] - gstart[g]), 1.f);
  float rc = 1.f / c;
  float4 s1 = *(const float4*)&S1[g * 128 + fq];
  float4 s2 = *(const float4*)&S2[g * 128 + fq];
  float4 ms = *(const float4*)&nms[fq];
  float4 w = *(const float4*)&nw[fq];
  float4 b = *(const float4*)&nb[fq];
  float4 hv = *(const float4*)&h[(size_t)n * 128 + fq];
  float4 o;
#define GN1(X)                                                           \
  {                                                                      \
    float mean = s1.X * rc;                                              \
    float var = s2.X * rc - mean * mean * ms.X * (2.f - ms.X);           \
    var = fmaxf(var, 0.f);                                               \
    float ot = (hv.X - ms.X * mean) * rsqrtf(var + 1e-5f);               \
    float t = w.X * ot + b.X;                                            \
    o.X = t > 0.f ? t : 0.f;                                             \
  }
  GN1(x) GN1(y) GN1(z) GN1(w)
#undef GN1
  ushort4* xp = (ushort4*)&xb[(size_t)n * 128 + fq];
  float4 xo = o;
  if (layer != 0) {
    ushort4 pv = *xp;
    xo.x += b2f(pv.x); xo.y += b2f(pv.y); xo.z += b2f(pv.z); xo.w += b2f(pv.w);
  }
  ushort4 bo;
  bo.x = f2b(xo.x); bo.y = f2b(xo.y); bo.z = f2b(xo.z); bo.w = f2b(xo.w);
  *xp = bo;
}

// ---------------------------------------------------------------- node MLPs (MFMA) + fused per-graph pooling
__global__ __launch_bounds__(256) void node_mlps_pool(
    const unsigned short* __restrict__ XB, const unsigned short* __restrict__ Fn,
    const float* __restrict__ hb1, const float* __restrict__ ab1,
    const float* __restrict__ hW2, const float* __restrict__ hb2,
    const float* __restrict__ aW2, const float* __restrict__ ab2,
    const int* __restrict__ batch, float* __restrict__ hub_feat,
    float* __restrict__ w_att, float* __restrict__ Sx, unsigned* __restrict__ Mx,
    float* __restrict__ WSx, float* __restrict__ Shub) {
  __shared__ float Hs[64 * 133];  // 34 KB
  __shared__ float Hf[64 * 4];
  __shared__ float Wa[64];
  int tid = threadIdx.x;
  int w = tid >> 6, lane = tid & 63;
  int row0 = blockIdx.x * 64;
  int row = row0 + w * 16 + (lane & 15);
  const unsigned short* xp = (row < NN) ? &XB[(size_t)row * 128] : &XB[0];
  bf16x8 a[4];
  load_a_frags_b16(xp, lane, a);
  f32x4 acc[8];
#pragma unroll
  for (int ct = 0; ct < 8; ++ct) acc[ct] = (f32x4){0.f, 0.f, 0.f, 0.f};
#pragma unroll
  for (int ct = 0; ct < 8; ++ct) {
#pragma unroll
    for (int ks = 0; ks < 4; ++ks) {
      bf16x8 b = *(const bf16x8*)&Fn[((ct * 4 + ks) * 64 + lane) * 8];
      acc[ct] = __builtin_amdgcn_mfma_f32_16x16x32_bf16(a[ks], b, acc[ct], 0, 0, 0);
    }
  }
#pragma unroll
  for (int ct = 0; ct < 8; ++ct) {
    int c = (ct << 4) + (lane & 15);
    float bias = (c < 64) ? hb1[c] : ab1[c - 64];
#pragma unroll
    for (int j = 0; j < 4; ++j) {
      int r = w * 16 + ((lane >> 4) << 2) + j;
      float v = acc[ct][j] + bias;
      Hs[r * 133 + c] = v > 0.f ? v : 0.f;
    }
  }
  __syncthreads();
  {
    int r = tid & 63, o = tid >> 6;
    int n = row0 + r;
    if (n < NN) {
      float d = hb2[o];
#pragma unroll 8
      for (int k = 0; k < 64; ++k) d += Hs[r * 133 + k] * hW2[k * 4 + o];
      hub_feat[n * 4 + o] = d;
      Hf[r * 4 + o] = d;
      if (tid < 64) {
        float d2 = ab2[0];
#pragma unroll 8
        for (int k = 0; k < 64; ++k) d2 += Hs[r * 133 + 64 + k] * aW2[k];
        w_att[n] = d2;
        Wa[r] = d2;
      }
    }
  }
  __syncthreads();
  // fused pooling over this block's 64 nodes (threads 0..127, f = tid)
  if (tid < 128) {
    int f = tid;
    int n0 = row0;
    int n1 = min(n0 + 64, NN);
    if (n0 < NN) {
      int g = batch[n0];
      float sx = 0.f, wx = 0.f, mx = 0.f, sh = 0.f;
      for (int n = n0; n < n1; ++n) {
        int gn = batch[n];
        if (gn != g) {
          atomicAdd(&Sx[g * 128 + f], sx);
          atomicAdd(&WSx[g * 128 + f], wx);
          atomicMax(&Mx[g * 128 + f], __float_as_uint(mx));
          if (f < 4) atomicAdd(&Shub[g * 4 + f], sh);
          sx = 0.f; wx = 0.f; mx = 0.f; sh = 0.f; g = gn;
        }
        float xv = b2f(XB[(size_t)n * 128 + f]);
        float ew = __expf(Wa[n - n0]);
        sx += xv;
        wx += ew * xv;
        mx = fmaxf(mx, xv);
        if (f < 4) sh += Hf[(n - n0) * 4 + f];
      }
      atomicAdd(&Sx[g * 128 + f], sx);
      atomicAdd(&WSx[g * 128 + f], wx);
      atomicMax(&Mx[g * 128 + f], __float_as_uint(mx));
      if (f < 4) atomicAdd(&Shub[g * 4 + f], sh);
    }
  }
}

// ---------------------------------------------------------------- global softmax denominator (atomic)
__global__ void reduce_sum1(const float* __restrict__ w, float* __restrict__ scal) {
  __shared__ float s[256];
  int t = threadIdx.x;
  float acc = 0.f;
  for (int i = blockIdx.x * 256 + t; i < NN; i += gridDim.x * 256) acc += __expf(w[i]);
  s[t] = acc;
  __syncthreads();
  for (int off = 128; off; off >>= 1) {
    if (t < off) s[t] += s[t + off];
    __syncthreads();
  }
  if (!t) atomicAdd(&scal[1], s[0]);
}

// ---------------------------------------------------------------- finalize: graph MLPs + outputs
__global__ __launch_bounds__(128) void finalize(
    const float* __restrict__ Sx, const float* __restrict__ Mx,
    const float* __restrict__ WSx, const float* __restrict__ Shub,
    const float* __restrict__ scal, const int* __restrict__ gstart,
    const int* __restrict__ cnt_src, const int* __restrict__ cnt_dst,
    const float* __restrict__ pW1, const float* __restrict__ pb1,
    const float* __restrict__ pW2, const float* __restrict__ pb2,
    const float* __restrict__ pW3, const float* __restrict__ pb3,
    const float* __restrict__ cW1, const float* __restrict__ cb1,
    const float* __restrict__ cW2, const float* __restrict__ cb2,
    const float* __restrict__ cW3, const float* __restrict__ cb3,
    float* __restrict__ out) {
  int g = blockIdx.x, t = threadIdx.x;
  __shared__ float pe[256], comb[140], buf1[128], buf2[64];
  __shared__ int snd[128];
  int s = gstart[g], e = gstart[g + 1];
  float c = fmaxf((float)(e - s), 1.f);
  int mdeg = 0;
  for (int n = s + t; n < e; n += 128) mdeg = max(mdeg, cnt_src[n] + cnt_dst[n]);
  snd[t] = mdeg;
  float* out_logits = out;                 // 128
  float* out_hub = out + 128;              // 64
  float* out_ge = out + 192;               // 8192
  float* out_hp = out + 192 + 8192;        // 256
  float* out_pf = out + 192 + 8192 + 256;  // 512
  float ge = WSx[g * 128 + t] / scal[1];
  out_ge[g * 128 + t] = ge;
  comb[t] = ge;
  pe[t] = Sx[g * 128 + t] / c;
  pe[128 + t] = Mx[g * 128 + t];
  if (t < 4) {
    float hp = Shub[g * 4 + t] / c;
    out_hp[g * 4 + t] = hp;
    comb[128 + t] = hp;
  }
  __syncthreads();
  for (int off = 64; off; off >>= 1) {
    if (t < off) snd[t] = max(snd[t], snd[t + off]);
    __syncthreads();
  }
  if (t == 0) out_hub[g] = (snd[0] > 0) ? 1.f : 0.f;
  // pattern MLP
  float v = pb1[t];
  for (int k = 0; k < 256; ++k) v += pe[k] * pW1[k * 128 + t];
  buf1[t] = v > 0.f ? v : 0.f;
  __syncthreads();
  if (t < 64) {
    float v2 = pb2[t];
    for (int k = 0; k < 128; ++k) v2 += buf1[k] * pW2[k * 64 + t];
    buf2[t] = v2 > 0.f ? v2 : 0.f;
  }
  __syncthreads();
  if (t < 8) {
    float v3 = pb3[t];
    for (int k = 0; k < 64; ++k) v3 += buf2[k] * pW3[k * 8 + t];
    out_pf[g * 8 + t] = v3;
    comb[132 + t] = v3;
  }
  __syncthreads();
  // classifier
  float u = cb1[t];
  for (int k = 0; k < 140; ++k) u += comb[k] * cW1[k * 128 + t];
  buf1[t] = u > 0.f ? u : 0.f;
  __syncthreads();
  if (t < 64) {
    float u2 = cb2[t];
    for (int k = 0; k < 128; ++k) u2 += buf1[k] * cW2[k * 64 + t];
    buf2[t] = u2 > 0.f ? u2 : 0.f;
  }
  __syncthreads();
  if (t < 2) {
    float u3 = cb3[t];
    for (int k = 0; k < 64; ++k) u3 += buf2[k] * cW3[k * 2 + t];
    out_logits[g * 2 + t] = u3;
  }
}

// ---------------------------------------------------------------- launch
extern "C" void kernel_launch(void* const* d_in, const int* in_sizes, int n_in,
                              void* d_out, int out_size, void* d_ws, size_t ws_size,
                              hipStream_t stream) {
  const float* x_in = (const float*)d_in[0];
  const int* ei = (const int*)d_in[1];
  const int* batch = (const int*)d_in[2];
  const float* proj_W = (const float*)d_in[3];
  const float* proj_b = (const float*)d_in[4];
  const float* gcn_W = (const float*)d_in[5];
  const float* gcn_b = (const float*)d_in[6];
  const float* gat_W = (const float*)d_in[7];
  const float* gat_as = (const float*)d_in[8];
  const float* gat_ad = (const float*)d_in[9];
  const float* gat_b = (const float*)d_in[10];
  const float* norm_w = (const float*)d_in[11];
  const float* norm_b = (const float*)d_in[12];
  const float* norm_ms = (const float*)d_in[13];
  const float* hub_W1 = (const float*)d_in[14];
  const float* hub_b1 = (const float*)d_in[15];
  const float* hub_W2 = (const float*)d_in[16];
  const float* hub_b2 = (const float*)d_in[17];
  const float* att_W1 = (const float*)d_in[18];
  const float* att_b1 = (const float*)d_in[19];
  const float* att_W2 = (const float*)d_in[20];
  const float* att_b2 = (const float*)d_in[21];
  const float* pat_W1 = (const float*)d_in[22];
  const float* pat_b1 = (const float*)d_in[23];
  const float* pat_W2 = (const float*)d_in[24];
  const float* pat_b2 = (const float*)d_in[25];
  const float* pat_W3 = (const float*)d_in[26];
  const float* pat_b3 = (const float*)d_in[27];
  const float* cls_W1 = (const float*)d_in[28];
  const float* cls_b1 = (const float*)d_in[29];
  const float* cls_W2 = (const float*)d_in[30];
  const float* cls_b2 = (const float*)d_in[31];
  const float* cls_W3 = (const float*)d_in[32];
  const float* cls_b3 = (const float*)d_in[33];
  float* out = (float*)d_out;

  char* ws = (char*)d_ws;
  auto fbuf = [&](size_t n) { float* p = (float*)ws; ws += ((n * 4 + 255) / 256) * 256; return p; };
  auto ibuf = [&](size_t n) { int* p = (int*)ws; ws += ((n * 4 + 255) / 256) * 256; return p; };

  // ---- zeroed-at-launch region (one memset): cnt_dst|cnt_src|fillpos + pool accums + scal
  int* zero0 = ibuf(3 * NN);
  int* cnt_dst = zero0;
  int* cnt_src = zero0 + NN;
  int* fillpos = zero0 + 2 * NN;
  float* Sx = fbuf(NG * 128);
  float* Mx = fbuf(NG * 128);
  float* WSx = fbuf(NG * 128);
  float* Shub = fbuf(NG * 4);
  float* scal = fbuf(4);
  size_t zbytes = (char*)ws - (char*)zero0;

  unsigned short* xb = (unsigned short*)fbuf((size_t)NN * 64);     // NN*128 bf16
  unsigned short* gath = (unsigned short*)fbuf((size_t)NN * 128);  // NN*256 bf16
  float* h = fbuf((size_t)NN * 128);
  unsigned short* wfrag = (unsigned short*)fbuf(3 * 32768 / 2);
  unsigned short* nfrag = (unsigned short*)fbuf(16384 / 2);
  unsigned short* pfrag = (unsigned short*)fbuf(16384 / 2);
  float* a_s = fbuf((size_t)NN * 4);
  float* a_d = fbuf((size_t)NN * 4);
  float* dis = fbuf(NN);
  float* w_att = fbuf(NN);
  float* hub_feat = fbuf((size_t)NN * 4);
  float* S1 = fbuf(NG * 128);  // S1|S2 contiguous (zeroed by gemm_dual block 0)
  float* S2 = fbuf(NG * 128);
  int* rowptr = ibuf(NN + 1);
  int* col = ibuf(NE);
  int* partial = ibuf(256);
  int* gstart = ibuf(NG + 1);

  const int NB = (NN + 255) / 256;   // 196
  const int GM = (NN + 63) / 64;     // 782 (mfma gemm / node chunks)

  // --- CSR + degrees + graph bounds + weight packing
  hipMemsetAsync(zero0, 0, zbytes, stream);
  count_edges<<<NE / 256, 256, 0, stream>>>(ei, cnt_dst, cnt_src);
  scanA_dis<<<NB, 256, 0, stream>>>(cnt_dst, partial, dis);
  scanB_bounds<<<1, 128, 0, stream>>>(partial, NB, batch, gstart);
  scanC<<<NB, 256, 0, stream>>>(cnt_dst, partial, rowptr);
  fill_edges<<<NE / 256, 256, 0, stream>>>(ei, rowptr, fillpos, col);
  prep_all<<<dim3(64, 5), 256, 0, stream>>>(gcn_W, gat_W, hub_W1, att_W1, proj_W,
                                            wfrag, nfrag, pfrag);

  // --- projection (MFMA, bf16 out)
  gemm_proj_mfma<<<GM, 256, 0, stream>>>(x_in, pfrag, proj_b, xb, NN);

  // --- layers
  for (int l = 0; l < 3; ++l) {
    gemm_dual_mfma<<<GM, 256, 0, stream>>>(xb, wfrag + (size_t)l * 32768,
                                           wfrag + (size_t)l * 32768 + 16384,
                                           gat_as + l * 128, gat_ad + l * 128, dis,
                                           gath, a_s, a_d, S1, NN);
    edge_aggregate_p<<<NN / 4, 256, 0, stream>>>(gath, a_s, a_d, dis, rowptr, col, batch,
                                                 gcn_b + l * 128, gat_b + l * 128, h, S1, S2);
    graph_norm<<<(NN * 32 + 255) / 256, 256, 0, stream>>>(h, batch, gstart, S1, S2,
                                                          norm_w + l * 128, norm_b + l * 128,
                                                          norm_ms + l * 128, xb, l);
  }

  // --- node MLPs + fused per-graph pooling
  node_mlps_pool<<<GM, 256, 0, stream>>>(xb, nfrag, hub_b1, att_b1, hub_W2, hub_b2,
                                         att_W2, att_b2, batch, hub_feat, w_att,
                                         Sx, (unsigned*)Mx, WSx, Shub);

  // --- global softmax denominator
  reduce_sum1<<<256, 256, 0, stream>>>(w_att, scal);

  // --- finalize: graph-level MLPs + all outputs
  finalize<<<NG, 128, 0, stream>>>(Sx, Mx, WSx, Shub, scal, gstart, cnt_src, cnt_dst,
                                   pat_W1, pat_b1, pat_W2, pat_b2, pat_W3, pat_b3,
                                   cls_W1, cls_b1, cls_W2, cls_b2, cls_W3, cls_b3, out);
}

// Round 10
// 562.305 us; speedup vs baseline: 1.2829x; 1.2829x over previous
//
#include <hip/hip_runtime.h>

#define NN 50000
#define NE 800000
#define NG 64
#define HID 128

typedef __attribute__((ext_vector_type(8))) short bf16x8;
typedef __attribute__((ext_vector_type(4))) float f32x4;

// bf16 helpers (RNE)
__device__ __forceinline__ unsigned short f2b(float f) {
  unsigned u = __float_as_uint(f);
  u += 0x7fffu + ((u >> 16) & 1u);
  return (unsigned short)(u >> 16);
}
__device__ __forceinline__ float b2f(unsigned short b) {
  return __uint_as_float(((unsigned)b) << 16);
}

// ---------------------------------------------------------------- CSR build
__global__ void count_edges(const int* __restrict__ ei, int* __restrict__ cnt_dst,
                            int* __restrict__ cnt_src) {
  int e = blockIdx.x * 256 + threadIdx.x;
  if (e >= NE) return;
  atomicAdd(&cnt_src[ei[e]], 1);
  atomicAdd(&cnt_dst[ei[NE + e]], 1);
}

__global__ void scanA_dis(const int* __restrict__ cnt, int* __restrict__ partial,
                          float* __restrict__ dis) {
  __shared__ int s[256];
  int t = threadIdx.x;
  int i = blockIdx.x * 256 + t;
  int v = (i < NN) ? cnt[i] : 0;
  if (i < NN) dis[i] = rsqrtf((float)(v + 1));  // +1 self loop
  s[t] = v;
  __syncthreads();
  for (int off = 128; off; off >>= 1) {
    if (t < off) s[t] += s[t + off];
    __syncthreads();
  }
  if (!t) partial[blockIdx.x] = s[0];
}

__global__ void scanB_bounds(int* __restrict__ partial, int nb,
                             const int* __restrict__ batch, int* __restrict__ gstart) {
  int t = threadIdx.x;
  if (t == 0) {
    int acc = 0;
    for (int i = 0; i < nb; ++i) { int v = partial[i]; partial[i] = acc; acc += v; }
  }
  if (t >= 1 && t <= NG + 1) {
    int g = t - 1;
    int lo = 0, hi = NN;
    while (lo < hi) { int mid = (lo + hi) >> 1; if (batch[mid] < g) lo = mid + 1; else hi = mid; }
    gstart[g] = lo;
  }
}

__global__ void scanC(const int* __restrict__ cnt, const int* __restrict__ partial,
                      int* __restrict__ rowptr) {
  __shared__ int bufA[256], bufB[256];
  int t = threadIdx.x;
  int i = blockIdx.x * 256 + t;
  int v = (i < NN) ? cnt[i] : 0;
  bufA[t] = v;
  __syncthreads();
  int* src = bufA; int* dst = bufB;
  for (int off = 1; off < 256; off <<= 1) {
    int x = src[t];
    if (t >= off) x += src[t - off];
    dst[t] = x;
    __syncthreads();
    int* tmp = src; src = dst; dst = tmp;
  }
  int incl = src[t];
  if (i < NN) rowptr[i] = partial[blockIdx.x] + incl - v;
  if (i == NN - 1) rowptr[NN] = partial[blockIdx.x] + incl;
}

__global__ void fill_edges(const int* __restrict__ ei, const int* __restrict__ rowptr,
                           int* __restrict__ fillpos, int* __restrict__ col) {
  int e = blockIdx.x * 256 + threadIdx.x;
  if (e >= NE) return;
  int s = ei[e], d = ei[NE + e];
  int p = atomicAdd(&fillpos[d], 1);
  col[rowptr[d] + p] = s;
}

// ---------------------------------------------------------------- fragment pack (all matrices)
__global__ void prep_all(const float* __restrict__ gcn_W, const float* __restrict__ gat_W,
                         const float* __restrict__ hW1, const float* __restrict__ aW1,
                         const float* __restrict__ projW, unsigned short* __restrict__ wfrag,
                         unsigned short* __restrict__ nfrag, unsigned short* __restrict__ pfrag) {
  int m = blockIdx.y;
  int idx = blockIdx.x * 256 + threadIdx.x;  // 0..16383
  int j = idx & 7, lane = (idx >> 3) & 63, t = idx >> 9;
  int ct = t >> 2, ks = t & 3;
  int k = ks * 32 + ((lane >> 4) << 3) + j;
  int c = (ct << 4) + (lane & 15);
  if (m < 3) {
    wfrag[(size_t)m * 32768 + idx] = f2b(gcn_W[(size_t)m * 16384 + k * 128 + c]);
    wfrag[(size_t)m * 32768 + 16384 + idx] = f2b(gat_W[(size_t)m * 16384 + k * 128 + c]);
  } else if (m == 3) {
    float v = (c < 64) ? hW1[k * 64 + c] : aW1[k * 64 + (c - 64)];
    nfrag[idx] = f2b(v);
  } else {
    pfrag[idx] = f2b(projW[k * 128 + c]);
  }
}

// ---------------------------------------------------------------- A-fragment loaders
__device__ __forceinline__ void load_a_frags_f32(const float* __restrict__ xp, int lane,
                                                 bf16x8 a[4]) {
#pragma unroll
  for (int ks = 0; ks < 4; ++ks) {
    int k0 = ks * 32 + ((lane >> 4) << 3);
    float4 u = *(const float4*)&xp[k0];
    float4 v = *(const float4*)&xp[k0 + 4];
    bf16x8 t;
    t[0] = (short)f2b(u.x); t[1] = (short)f2b(u.y); t[2] = (short)f2b(u.z); t[3] = (short)f2b(u.w);
    t[4] = (short)f2b(v.x); t[5] = (short)f2b(v.y); t[6] = (short)f2b(v.z); t[7] = (short)f2b(v.w);
    a[ks] = t;
  }
}

__device__ __forceinline__ void load_a_frags_b16(const unsigned short* __restrict__ xp,
                                                 int lane, bf16x8 a[4]) {
#pragma unroll
  for (int ks = 0; ks < 4; ++ks) {
    int k0 = ks * 32 + ((lane >> 4) << 3);
    a[ks] = *(const bf16x8*)&xp[k0];
  }
}

// ---------------------------------------------------------------- projection MFMA GEMM -> bf16 xb
__global__ __launch_bounds__(256) void gemm_proj_mfma(
    const float* __restrict__ X, const unsigned short* __restrict__ F,
    const float* __restrict__ bias, unsigned short* __restrict__ XB, int nrows) {
  __shared__ unsigned short Ys[64 * 128];  // 16 KB
  int tid = threadIdx.x;
  int w = tid >> 6, lane = tid & 63;
  int row0 = blockIdx.x * 64;
  int row = row0 + w * 16 + (lane & 15);
  const float* xp = (row < nrows) ? &X[(size_t)row * 128] : &X[0];
  bf16x8 a[4];
  load_a_frags_f32(xp, lane, a);
  f32x4 acc[8];
#pragma unroll
  for (int ct = 0; ct < 8; ++ct) acc[ct] = (f32x4){0.f, 0.f, 0.f, 0.f};
#pragma unroll
  for (int ct = 0; ct < 8; ++ct) {
#pragma unroll
    for (int ks = 0; ks < 4; ++ks) {
      bf16x8 b = *(const bf16x8*)&F[((ct * 4 + ks) * 64 + lane) * 8];
      acc[ct] = __builtin_amdgcn_mfma_f32_16x16x32_bf16(a[ks], b, acc[ct], 0, 0, 0);
    }
  }
#pragma unroll
  for (int ct = 0; ct < 8; ++ct) {
    int c = (ct << 4) + (lane & 15);
    float bv = bias[c];
#pragma unroll
    for (int j = 0; j < 4; ++j) {
      int r = w * 16 + ((lane >> 4) << 2) + j;
      Ys[r * 128 + c] = f2b(acc[ct][j] + bv);
    }
  }
  __syncthreads();
  int nr = min(nrows - row0, 64);
  const uint4* ys4 = (const uint4*)Ys;
  uint4* y4 = (uint4*)(XB + (size_t)row0 * 128);
  for (int e = tid; e < nr * 16; e += 256) y4[e] = ys4[e];
}

// ---------------------------------------------------------------- dual MFMA GEMM -> G + fused GAT scores
// block 0 zeroes S1/S2 for the later graph_stats kernel.
__global__ __launch_bounds__(256) void gemm_dual_mfma(
    const unsigned short* __restrict__ XB, const unsigned short* __restrict__ F1,
    const unsigned short* __restrict__ F2, const float* __restrict__ asrc,
    const float* __restrict__ adst, const float* __restrict__ dis,
    unsigned short* __restrict__ G, float* __restrict__ a_s, float* __restrict__ a_d,
    float* __restrict__ S1z, int nrows) {
  if (blockIdx.x == 0) {
    for (int i = threadIdx.x; i < 2 * NG * 128; i += 256) S1z[i] = 0.f;
  }
  __shared__ unsigned short Gs[64 * 256];  // 32 KB
  int tid = threadIdx.x;
  int w = tid >> 6, lane = tid & 63;
  int row0 = blockIdx.x * 64;
  int row = row0 + w * 16 + (lane & 15);
  const unsigned short* xp = (row < nrows) ? &XB[(size_t)row * 128] : &XB[0];
  bf16x8 a[4];
  load_a_frags_b16(xp, lane, a);
  f32x4 acc1[8], acc2[8];
#pragma unroll
  for (int ct = 0; ct < 8; ++ct) {
    acc1[ct] = (f32x4){0.f, 0.f, 0.f, 0.f};
    acc2[ct] = (f32x4){0.f, 0.f, 0.f, 0.f};
  }
#pragma unroll
  for (int ct = 0; ct < 8; ++ct) {
#pragma unroll
    for (int ks = 0; ks < 4; ++ks) {
      int off = ((ct * 4 + ks) * 64 + lane) * 8;
      bf16x8 b1 = *(const bf16x8*)&F1[off];
      bf16x8 b2 = *(const bf16x8*)&F2[off];
      acc1[ct] = __builtin_amdgcn_mfma_f32_16x16x32_bf16(a[ks], b1, acc1[ct], 0, 0, 0);
      acc2[ct] = __builtin_amdgcn_mfma_f32_16x16x32_bf16(a[ks], b2, acc2[ct], 0, 0, 0);
    }
  }
  float dv[4];
#pragma unroll
  for (int j = 0; j < 4; ++j) {
    int gr = row0 + w * 16 + ((lane >> 4) << 2) + j;
    dv[j] = dis[gr < nrows ? gr : 0];
  }
#pragma unroll
  for (int ct = 0; ct < 8; ++ct) {
#pragma unroll
    for (int j = 0; j < 4; ++j) {
      int r = w * 16 + ((lane >> 4) << 2) + j;
      int c = (ct << 4) + (lane & 15);
      Gs[r * 256 + c] = f2b(acc1[ct][j] * dv[j]);
      Gs[r * 256 + 128 + c] = f2b(acc2[ct][j]);
    }
  }
  __syncthreads();
  int nr = min(nrows - row0, 64);
  const uint4* gs4 = (const uint4*)Gs;
  uint4* g4 = (uint4*)(G + (size_t)row0 * 256);
  for (int e = tid; e < nr * 32; e += 256) g4[e] = gs4[e];
  // fused attention scores from the LDS tile
  int f = 2 * lane;
  float as0 = asrc[f], as1 = asrc[f + 1];
  float ad0 = adst[f], ad1 = adst[f + 1];
  for (int i = 0; i < 16; ++i) {
    int r = w * 16 + i;
    int n = row0 + r;
    if (n >= nrows) break;
    ushort2 v = *(const ushort2*)&Gs[r * 256 + 128 + f];
    float x0 = b2f(v.x), x1 = b2f(v.y);
    float ps = x0 * as0 + x1 * as1;
    float pd = x0 * ad0 + x1 * ad1;
    ps += __shfl_xor(ps, 1); pd += __shfl_xor(pd, 1);
    ps += __shfl_xor(ps, 2); pd += __shfl_xor(pd, 2);
    ps += __shfl_xor(ps, 4); pd += __shfl_xor(pd, 4);
    ps += __shfl_xor(ps, 8); pd += __shfl_xor(pd, 8);
    if ((lane & 15) == 0) {
      int h = lane >> 4;
      a_s[n * 4 + h] = ps;
      a_d[n * 4 + h] = pd;
    }
  }
}

// ---------------------------------------------------------------- edge aggregation (edge-parallel, R8 form)
__device__ __forceinline__ float lrelu(float v) { return v > 0.f ? v : 0.2f * v; }

__global__ __launch_bounds__(256) void edge_aggregate_p(
    const unsigned short* __restrict__ G, const float* __restrict__ a_s,
    const float* __restrict__ a_d, const float* __restrict__ dis,
    const int* __restrict__ rowptr, const int* __restrict__ col,
    const float* __restrict__ gcn_b, const float* __restrict__ gat_b,
    float* __restrict__ hout) {
  int n = blockIdx.x * 4 + (threadIdx.x >> 6);
  int lane = threadIdx.x & 63;
  int es = lane >> 4, fl = lane & 15;
  int h = fl >> 2;
  int f8 = fl << 3;
  int p0 = rowptr[n], p1 = rowptr[n + 1];
  int cnt = p1 - p0 + 1;  // + self loop
  float adh = a_d[n * 4 + h];
  float dn = dis[n];
  float ag[8] = {0.f, 0.f, 0.f, 0.f, 0.f, 0.f, 0.f, 0.f};
  float aa[8] = {0.f, 0.f, 0.f, 0.f, 0.f, 0.f, 0.f, 0.f};
  float ssum = 0.f;
#define EDGE_ACC(eu, xv, hv)                                \
  do {                                                      \
    ag[0] += __uint_as_float((xv).x << 16);                 \
    ag[1] += __uint_as_float((xv).x & 0xffff0000u);         \
    ag[2] += __uint_as_float((xv).y << 16);                 \
    ag[3] += __uint_as_float((xv).y & 0xffff0000u);         \
    ag[4] += __uint_as_float((xv).z << 16);                 \
    ag[5] += __uint_as_float((xv).z & 0xffff0000u);         \
    ag[6] += __uint_as_float((xv).w << 16);                 \
    ag[7] += __uint_as_float((xv).w & 0xffff0000u);         \
    aa[0] += (eu)*__uint_as_float((hv).x << 16);            \
    aa[1] += (eu)*__uint_as_float((hv).x & 0xffff0000u);    \
    aa[2] += (eu)*__uint_as_float((hv).y << 16);            \
    aa[3] += (eu)*__uint_as_float((hv).y & 0xffff0000u);    \
    aa[4] += (eu)*__uint_as_float((hv).z << 16);            \
    aa[5] += (eu)*__uint_as_float((hv).z & 0xffff0000u);    \
    aa[6] += (eu)*__uint_as_float((hv).w << 16);            \
    aa[7] += (eu)*__uint_as_float((hv).w & 0xffff0000u);    \
  } while (0)
  int e = es;
  for (; e + 4 < cnt; e += 8) {
    int eB = e + 4;
    int srcA = (e < cnt - 1) ? col[p0 + e] : n;
    int srcB = (eB < cnt - 1) ? col[p0 + eB] : n;
    float euA = __expf(lrelu(a_s[srcA * 4 + h] + adh));
    float euB = __expf(lrelu(a_s[srcB * 4 + h] + adh));
    uint4 xvA = *(const uint4*)&G[(size_t)srcA * 256 + f8];
    uint4 hvA = *(const uint4*)&G[(size_t)srcA * 256 + 128 + f8];
    uint4 xvB = *(const uint4*)&G[(size_t)srcB * 256 + f8];
    uint4 hvB = *(const uint4*)&G[(size_t)srcB * 256 + 128 + f8];
    ssum += euA + euB;
    EDGE_ACC(euA, xvA, hvA);
    EDGE_ACC(euB, xvB, hvB);
  }
  for (; e < cnt; e += 4) {
    int src = (e < cnt - 1) ? col[p0 + e] : n;
    float eu = __expf(lrelu(a_s[src * 4 + h] + adh));
    uint4 xv = *(const uint4*)&G[(size_t)src * 256 + f8];
    uint4 hv = *(const uint4*)&G[(size_t)src * 256 + 128 + f8];
    ssum += eu;
    EDGE_ACC(eu, xv, hv);
  }
#undef EDGE_ACC
#pragma unroll
  for (int j = 0; j < 8; ++j) {
    ag[j] += __shfl_xor(ag[j], 16); ag[j] += __shfl_xor(ag[j], 32);
    aa[j] += __shfl_xor(aa[j], 16); aa[j] += __shfl_xor(aa[j], 32);
  }
  ssum += __shfl_xor(ssum, 16); ssum += __shfl_xor(ssum, 32);
  if (es == 0) {
    float rs = 1.f / ssum;
    float4 gb0 = *(const float4*)&gcn_b[f8];
    float4 gb1 = *(const float4*)&gcn_b[f8 + 4];
    float4 tb0 = *(const float4*)&gat_b[f8];
    float4 tb1 = *(const float4*)&gat_b[f8 + 4];
    float4 o0, o1;
    o0.x = ag[0] * dn + aa[0] * rs + gb0.x + tb0.x;
    o0.y = ag[1] * dn + aa[1] * rs + gb0.y + tb0.y;
    o0.z = ag[2] * dn + aa[2] * rs + gb0.z + tb0.z;
    o0.w = ag[3] * dn + aa[3] * rs + gb0.w + tb0.w;
    o1.x = ag[4] * dn + aa[4] * rs + gb1.x + tb1.x;
    o1.y = ag[5] * dn + aa[5] * rs + gb1.y + tb1.y;
    o1.z = ag[6] * dn + aa[6] * rs + gb1.z + tb1.z;
    o1.w = ag[7] * dn + aa[7] * rs + gb1.w + tb1.w;
    *(float4*)&hout[n * 128 + f8] = o0;
    *(float4*)&hout[n * 128 + f8 + 4] = o1;
  }
}

// ---------------------------------------------------------------- GraphNorm stats (node-chunk-parallel, R8 form)
__global__ __launch_bounds__(128) void graph_stats_par(
    const float* __restrict__ h, const int* __restrict__ batch,
    float* __restrict__ S1, float* __restrict__ S2) {
  int f = threadIdx.x;
  int n0 = blockIdx.x * 64;
  int n1 = min(n0 + 64, NN);
  int g = batch[n0];
  float s1 = 0.f, s2 = 0.f;
  for (int n = n0; n < n1; ++n) {
    int gn = batch[n];
    if (gn != g) {
      atomicAdd(&S1[g * 128 + f], s1);
      atomicAdd(&S2[g * 128 + f], s2);
      s1 = 0.f; s2 = 0.f; g = gn;
    }
    float v = h[n * 128 + f];
    s1 += v; s2 += v * v;
  }
  atomicAdd(&S1[g * 128 + f], s1);
  atomicAdd(&S2[g * 128 + f], s2);
}

// ---------------------------------------------------------------- GraphNorm apply (bf16 x)
__global__ __launch_bounds__(256) void graph_norm(
    const float* __restrict__ h, const int* __restrict__ batch,
    const int* __restrict__ gstart, const float* __restrict__ S1,
    const float* __restrict__ S2, const float* __restrict__ nw,
    const float* __restrict__ nb, const float* __restrict__ nms,
    unsigned short* __restrict__ xb, int layer) {
  int idx = blockIdx.x * 256 + threadIdx.x;  // one float4 per thread
  if (idx >= NN * 32) return;
  int n = idx >> 5, fq = (idx & 31) << 2;
  int g = batch[n];
  float c = fmaxf((float)(gstart[g + 1] - gstart[g]), 1.f);
  float rc = 1.f / c;
  float4 s1 = *(const float4*)&S1[g * 128 + fq];
  float4 s2 = *(const float4*)&S2[g * 128 + fq];
  float4 ms = *(const float4*)&nms[fq];
  float4 w = *(const float4*)&nw[fq];
  float4 b = *(const float4*)&nb[fq];
  float4 hv = *(const float4*)&h[(size_t)n * 128 + fq];
  float4 o;
#define GN1(X)                                                           \
  {                                                                      \
    float mean = s1.X * rc;                                              \
    float var = s2.X * rc - mean * mean * ms.X * (2.f - ms.X);           \
    var = fmaxf(var, 0.f);                                               \
    float ot = (hv.X - ms.X * mean) * rsqrtf(var + 1e-5f);               \
    float t = w.X * ot + b.X;                                            \
    o.X = t > 0.f ? t : 0.f;                                             \
  }
  GN1(x) GN1(y) GN1(z) GN1(w)
#undef GN1
  ushort4* xp = (ushort4*)&xb[(size_t)n * 128 + fq];
  float4 xo = o;
  if (layer != 0) {
    ushort4 pv = *xp;
    xo.x += b2f(pv.x); xo.y += b2f(pv.y); xo.z += b2f(pv.z); xo.w += b2f(pv.w);
  }
  ushort4 bo;
  bo.x = f2b(xo.x); bo.y = f2b(xo.y); bo.z = f2b(xo.z); bo.w = f2b(xo.w);
  *xp = bo;
}

// ---------------------------------------------------------------- node MLPs (MFMA) + fused per-graph pooling
__global__ __launch_bounds__(256) void node_mlps_pool(
    const unsigned short* __restrict__ XB, const unsigned short* __restrict__ Fn,
    const float* __restrict__ hb1, const float* __restrict__ ab1,
    const float* __restrict__ hW2, const float* __restrict__ hb2,
    const float* __restrict__ aW2, const float* __restrict__ ab2,
    const int* __restrict__ batch, float* __restrict__ hub_feat,
    float* __restrict__ w_att, float* __restrict__ Sx, unsigned* __restrict__ Mx,
    float* __restrict__ WSx, float* __restrict__ Shub) {
  __shared__ float Hs[64 * 133];  // 34 KB
  __shared__ float Hf[64 * 4];
  __shared__ float Wa[64];
  int tid = threadIdx.x;
  int w = tid >> 6, lane = tid & 63;
  int row0 = blockIdx.x * 64;
  int row = row0 + w * 16 + (lane & 15);
  const unsigned short* xp = (row < NN) ? &XB[(size_t)row * 128] : &XB[0];
  bf16x8 a[4];
  load_a_frags_b16(xp, lane, a);
  f32x4 acc[8];
#pragma unroll
  for (int ct = 0; ct < 8; ++ct) acc[ct] = (f32x4){0.f, 0.f, 0.f, 0.f};
#pragma unroll
  for (int ct = 0; ct < 8; ++ct) {
#pragma unroll
    for (int ks = 0; ks < 4; ++ks) {
      bf16x8 b = *(const bf16x8*)&Fn[((ct * 4 + ks) * 64 + lane) * 8];
      acc[ct] = __builtin_amdgcn_mfma_f32_16x16x32_bf16(a[ks], b, acc[ct], 0, 0, 0);
    }
  }
#pragma unroll
  for (int ct = 0; ct < 8; ++ct) {
    int c = (ct << 4) + (lane & 15);
    float bias = (c < 64) ? hb1[c] : ab1[c - 64];
#pragma unroll
    for (int j = 0; j < 4; ++j) {
      int r = w * 16 + ((lane >> 4) << 2) + j;
      float v = acc[ct][j] + bias;
      Hs[r * 133 + c] = v > 0.f ? v : 0.f;
    }
  }
  __syncthreads();
  {
    int r = tid & 63, o = tid >> 6;
    int n = row0 + r;
    if (n < NN) {
      float d = hb2[o];
#pragma unroll 8
      for (int k = 0; k < 64; ++k) d += Hs[r * 133 + k] * hW2[k * 4 + o];
      hub_feat[n * 4 + o] = d;
      Hf[r * 4 + o] = d;
      if (tid < 64) {
        float d2 = ab2[0];
#pragma unroll 8
        for (int k = 0; k < 64; ++k) d2 += Hs[r * 133 + 64 + k] * aW2[k];
        w_att[n] = d2;
        Wa[r] = d2;
      }
    }
  }
  __syncthreads();
  // fused pooling over this block's 64 nodes (threads 0..127, f = tid)
  if (tid < 128) {
    int f = tid;
    int n0 = row0;
    int n1 = min(n0 + 64, NN);
    if (n0 < NN) {
      int g = batch[n0];
      float sx = 0.f, wx = 0.f, mx = 0.f, sh = 0.f;
      for (int n = n0; n < n1; ++n) {
        int gn = batch[n];
        if (gn != g) {
          atomicAdd(&Sx[g * 128 + f], sx);
          atomicAdd(&WSx[g * 128 + f], wx);
          atomicMax(&Mx[g * 128 + f], __float_as_uint(mx));
          if (f < 4) atomicAdd(&Shub[g * 4 + f], sh);
          sx = 0.f; wx = 0.f; mx = 0.f; sh = 0.f; g = gn;
        }
        float xv = b2f(XB[(size_t)n * 128 + f]);
        float ew = __expf(Wa[n - n0]);
        sx += xv;
        wx += ew * xv;
        mx = fmaxf(mx, xv);
        if (f < 4) sh += Hf[(n - n0) * 4 + f];
      }
      atomicAdd(&Sx[g * 128 + f], sx);
      atomicAdd(&WSx[g * 128 + f], wx);
      atomicMax(&Mx[g * 128 + f], __float_as_uint(mx));
      if (f < 4) atomicAdd(&Shub[g * 4 + f], sh);
    }
  }
}

// ---------------------------------------------------------------- global softmax denominator (atomic)
__global__ void reduce_sum1(const float* __restrict__ w, float* __restrict__ scal) {
  __shared__ float s[256];
  int t = threadIdx.x;
  float acc = 0.f;
  for (int i = blockIdx.x * 256 + t; i < NN; i += gridDim.x * 256) acc += __expf(w[i]);
  s[t] = acc;
  __syncthreads();
  for (int off = 128; off; off >>= 1) {
    if (t < off) s[t] += s[t + off];
    __syncthreads();
  }
  if (!t) atomicAdd(&scal[1], s[0]);
}

// ---------------------------------------------------------------- finalize: graph MLPs + outputs
__global__ __launch_bounds__(128) void finalize(
    const float* __restrict__ Sx, const float* __restrict__ Mx,
    const float* __restrict__ WSx, const float* __restrict__ Shub,
    const float* __restrict__ scal, const int* __restrict__ gstart,
    const int* __restrict__ cnt_src, const int* __restrict__ cnt_dst,
    const float* __restrict__ pW1, const float* __restrict__ pb1,
    const float* __restrict__ pW2, const float* __restrict__ pb2,
    const float* __restrict__ pW3, const float* __restrict__ pb3,
    const float* __restrict__ cW1, const float* __restrict__ cb1,
    const float* __restrict__ cW2, const float* __restrict__ cb2,
    const float* __restrict__ cW3, const float* __restrict__ cb3,
    float* __restrict__ out) {
  int g = blockIdx.x, t = threadIdx.x;
  __shared__ float pe[256], comb[140], buf1[128], buf2[64];
  __shared__ int snd[128];
  int s = gstart[g], e = gstart[g + 1];
  float c = fmaxf((float)(e - s), 1.f);
  int mdeg = 0;
  for (int n = s + t; n < e; n += 128) mdeg = max(mdeg, cnt_src[n] + cnt_dst[n]);
  snd[t] = mdeg;
  float* out_logits = out;                 // 128
  float* out_hub = out + 128;              // 64
  float* out_ge = out + 192;               // 8192
  float* out_hp = out + 192 + 8192;        // 256
  float* out_pf = out + 192 + 8192 + 256;  // 512
  float ge = WSx[g * 128 + t] / scal[1];
  out_ge[g * 128 + t] = ge;
  comb[t] = ge;
  pe[t] = Sx[g * 128 + t] / c;
  pe[128 + t] = Mx[g * 128 + t];
  if (t < 4) {
    float hp = Shub[g * 4 + t] / c;
    out_hp[g * 4 + t] = hp;
    comb[128 + t] = hp;
  }
  __syncthreads();
  for (int off = 64; off; off >>= 1) {
    if (t < off) snd[t] = max(snd[t], snd[t + off]);
    __syncthreads();
  }
  if (t == 0) out_hub[g] = (snd[0] > 0) ? 1.f : 0.f;
  // pattern MLP
  float v = pb1[t];
  for (int k = 0; k < 256; ++k) v += pe[k] * pW1[k * 128 + t];
  buf1[t] = v > 0.f ? v : 0.f;
  __syncthreads();
  if (t < 64) {
    float v2 = pb2[t];
    for (int k = 0; k < 128; ++k) v2 += buf1[k] * pW2[k * 64 + t];
    buf2[t] = v2 > 0.f ? v2 : 0.f;
  }
  __syncthreads();
  if (t < 8) {
    float v3 = pb3[t];
    for (int k = 0; k < 64; ++k) v3 += buf2[k] * pW3[k * 8 + t];
    out_pf[g * 8 + t] = v3;
    comb[132 + t] = v3;
  }
  __syncthreads();
  // classifier
  float u = cb1[t];
  for (int k = 0; k < 140; ++k) u += comb[k] * cW1[k * 128 + t];
  buf1[t] = u > 0.f ? u : 0.f;
  __syncthreads();
  if (t < 64) {
    float u2 = cb2[t];
    for (int k = 0; k < 128; ++k) u2 += buf1[k] * cW2[k * 64 + t];
    buf2[t] = u2 > 0.f ? u2 : 0.f;
  }
  __syncthreads();
  if (t < 2) {
    float u3 = cb3[t];
    for (int k = 0; k < 64; ++k) u3 += buf2[k] * cW3[k * 2 + t];
    out_logits[g * 2 + t] = u3;
  }
}

// ---------------------------------------------------------------- launch
extern "C" void kernel_launch(void* const* d_in, const int* in_sizes, int n_in,
                              void* d_out, int out_size, void* d_ws, size_t ws_size,
                              hipStream_t stream) {
  const float* x_in = (const float*)d_in[0];
  const int* ei = (const int*)d_in[1];
  const int* batch = (const int*)d_in[2];
  const float* proj_W = (const float*)d_in[3];
  const float* proj_b = (const float*)d_in[4];
  const float* gcn_W = (const float*)d_in[5];
  const float* gcn_b = (const float*)d_in[6];
  const float* gat_W = (const float*)d_in[7];
  const float* gat_as = (const float*)d_in[8];
  const float* gat_ad = (const float*)d_in[9];
  const float* gat_b = (const float*)d_in[10];
  const float* norm_w = (const float*)d_in[11];
  const float* norm_b = (const float*)d_in[12];
  const float* norm_ms = (const float*)d_in[13];
  const float* hub_W1 = (const float*)d_in[14];
  const float* hub_b1 = (const float*)d_in[15];
  const float* hub_W2 = (const float*)d_in[16];
  const float* hub_b2 = (const float*)d_in[17];
  const float* att_W1 = (const float*)d_in[18];
  const float* att_b1 = (const float*)d_in[19];
  const float* att_W2 = (const float*)d_in[20];
  const float* att_b2 = (const float*)d_in[21];
  const float* pat_W1 = (const float*)d_in[22];
  const float* pat_b1 = (const float*)d_in[23];
  const float* pat_W2 = (const float*)d_in[24];
  const float* pat_b2 = (const float*)d_in[25];
  const float* pat_W3 = (const float*)d_in[26];
  const float* pat_b3 = (const float*)d_in[27];
  const float* cls_W1 = (const float*)d_in[28];
  const float* cls_b1 = (const float*)d_in[29];
  const float* cls_W2 = (const float*)d_in[30];
  const float* cls_b2 = (const float*)d_in[31];
  const float* cls_W3 = (const float*)d_in[32];
  const float* cls_b3 = (const float*)d_in[33];
  float* out = (float*)d_out;

  char* ws = (char*)d_ws;
  auto fbuf = [&](size_t n) { float* p = (float*)ws; ws += ((n * 4 + 255) / 256) * 256; return p; };
  auto ibuf = [&](size_t n) { int* p = (int*)ws; ws += ((n * 4 + 255) / 256) * 256; return p; };

  // ---- zeroed-at-launch region (one memset): cnt_dst|cnt_src|fillpos + pool accums + scal
  int* zero0 = ibuf(3 * NN);
  int* cnt_dst = zero0;
  int* cnt_src = zero0 + NN;
  int* fillpos = zero0 + 2 * NN;
  float* Sx = fbuf(NG * 128);
  float* Mx = fbuf(NG * 128);
  float* WSx = fbuf(NG * 128);
  float* Shub = fbuf(NG * 4);
  float* scal = fbuf(4);
  size_t zbytes = (char*)ws - (char*)zero0;

  unsigned short* xb = (unsigned short*)fbuf((size_t)NN * 64);     // NN*128 bf16
  unsigned short* gath = (unsigned short*)fbuf((size_t)NN * 128);  // NN*256 bf16
  float* h = fbuf((size_t)NN * 128);
  unsigned short* wfrag = (unsigned short*)fbuf(3 * 32768 / 2);
  unsigned short* nfrag = (unsigned short*)fbuf(16384 / 2);
  unsigned short* pfrag = (unsigned short*)fbuf(16384 / 2);
  float* a_s = fbuf((size_t)NN * 4);
  float* a_d = fbuf((size_t)NN * 4);
  float* dis = fbuf(NN);
  float* w_att = fbuf(NN);
  float* hub_feat = fbuf((size_t)NN * 4);
  float* S1 = fbuf(NG * 128);  // S1|S2 contiguous (zeroed by gemm_dual block 0)
  float* S2 = fbuf(NG * 128);
  int* rowptr = ibuf(NN + 1);
  int* col = ibuf(NE);
  int* partial = ibuf(256);
  int* gstart = ibuf(NG + 1);

  const int NB = (NN + 255) / 256;   // 196
  const int GM = (NN + 63) / 64;     // 782 (mfma gemm / node chunks)

  // --- CSR + degrees + graph bounds + weight packing
  hipMemsetAsync(zero0, 0, zbytes, stream);
  count_edges<<<NE / 256, 256, 0, stream>>>(ei, cnt_dst, cnt_src);
  scanA_dis<<<NB, 256, 0, stream>>>(cnt_dst, partial, dis);
  scanB_bounds<<<1, 128, 0, stream>>>(partial, NB, batch, gstart);
  scanC<<<NB, 256, 0, stream>>>(cnt_dst, partial, rowptr);
  fill_edges<<<NE / 256, 256, 0, stream>>>(ei, rowptr, fillpos, col);
  prep_all<<<dim3(64, 5), 256, 0, stream>>>(gcn_W, gat_W, hub_W1, att_W1, proj_W,
                                            wfrag, nfrag, pfrag);

  // --- projection (MFMA, bf16 out)
  gemm_proj_mfma<<<GM, 256, 0, stream>>>(x_in, pfrag, proj_b, xb, NN);

  // --- layers
  for (int l = 0; l < 3; ++l) {
    gemm_dual_mfma<<<GM, 256, 0, stream>>>(xb, wfrag + (size_t)l * 32768,
                                           wfrag + (size_t)l * 32768 + 16384,
                                           gat_as + l * 128, gat_ad + l * 128, dis,
                                           gath, a_s, a_d, S1, NN);
    edge_aggregate_p<<<NN / 4, 256, 0, stream>>>(gath, a_s, a_d, dis, rowptr, col,
                                                 gcn_b + l * 128, gat_b + l * 128, h);
    graph_stats_par<<<GM, 128, 0, stream>>>(h, batch, S1, S2);
    graph_norm<<<(NN * 32 + 255) / 256, 256, 0, stream>>>(h, batch, gstart, S1, S2,
                                                          norm_w + l * 128, norm_b + l * 128,
                                                          norm_ms + l * 128, xb, l);
  }

  // --- node MLPs + fused per-graph pooling
  node_mlps_pool<<<GM, 256, 0, stream>>>(xb, nfrag, hub_b1, att_b1, hub_W2, hub_b2,
                                         att_W2, att_b2, batch, hub_feat, w_att,
                                         Sx, (unsigned*)Mx, WSx, Shub);

  // --- global softmax denominator
  reduce_sum1<<<256, 256, 0, stream>>>(w_att, scal);

  // --- finalize: graph-level MLPs + all outputs
  finalize<<<NG, 128, 0, stream>>>(Sx, Mx, WSx, Shub, scal, gstart, cnt_src, cnt_dst,
                                   pat_W1, pat_b1, pat_W2, pat_b2, pat_W3, pat_b3,
                                   cls_W1, cls_b1, cls_W2, cls_b2, cls_W3, cls_b3, out);
}

// Round 11
// 554.431 us; speedup vs baseline: 1.3011x; 1.0142x over previous
//
#include <hip/hip_runtime.h>

#define NN 50000
#define NE 800000
#define NG 64
#define HID 128

typedef __attribute__((ext_vector_type(8))) short bf16x8;
typedef __attribute__((ext_vector_type(4))) float f32x4;

// bf16 helpers (RNE)
__device__ __forceinline__ unsigned short f2b(float f) {
  unsigned u = __float_as_uint(f);
  u += 0x7fffu + ((u >> 16) & 1u);
  return (unsigned short)(u >> 16);
}
__device__ __forceinline__ float b2f(unsigned short b) {
  return __uint_as_float(((unsigned)b) << 16);
}
__device__ __forceinline__ unsigned pack2(float lo, float hi) {
  return (unsigned)f2b(lo) | ((unsigned)f2b(hi) << 16);
}

// ---------------------------------------------------------------- CSR build
__global__ void count_edges(const int* __restrict__ ei, int* __restrict__ cnt_dst,
                            int* __restrict__ cnt_src) {
  int e = blockIdx.x * 256 + threadIdx.x;
  if (e >= NE) return;
  atomicAdd(&cnt_src[ei[e]], 1);
  atomicAdd(&cnt_dst[ei[NE + e]], 1);
}

__global__ void scanA_dis(const int* __restrict__ cnt, int* __restrict__ partial,
                          float* __restrict__ dis) {
  __shared__ int s[256];
  int t = threadIdx.x;
  int i = blockIdx.x * 256 + t;
  int v = (i < NN) ? cnt[i] : 0;
  if (i < NN) dis[i] = rsqrtf((float)(v + 1));  // +1 self loop
  s[t] = v;
  __syncthreads();
  for (int off = 128; off; off >>= 1) {
    if (t < off) s[t] += s[t + off];
    __syncthreads();
  }
  if (!t) partial[blockIdx.x] = s[0];
}

__global__ void scanB_bounds(int* __restrict__ partial, int nb,
                             const int* __restrict__ batch, int* __restrict__ gstart) {
  int t = threadIdx.x;
  if (t == 0) {
    int acc = 0;
    for (int i = 0; i < nb; ++i) { int v = partial[i]; partial[i] = acc; acc += v; }
  }
  if (t >= 1 && t <= NG + 1) {
    int g = t - 1;
    int lo = 0, hi = NN;
    while (lo < hi) { int mid = (lo + hi) >> 1; if (batch[mid] < g) lo = mid + 1; else hi = mid; }
    gstart[g] = lo;
  }
}

__global__ void scanC(const int* __restrict__ cnt, const int* __restrict__ partial,
                      int* __restrict__ rowptr) {
  __shared__ int bufA[256], bufB[256];
  int t = threadIdx.x;
  int i = blockIdx.x * 256 + t;
  int v = (i < NN) ? cnt[i] : 0;
  bufA[t] = v;
  __syncthreads();
  int* src = bufA; int* dst = bufB;
  for (int off = 1; off < 256; off <<= 1) {
    int x = src[t];
    if (t >= off) x += src[t - off];
    dst[t] = x;
    __syncthreads();
    int* tmp = src; src = dst; dst = tmp;
  }
  int incl = src[t];
  if (i < NN) rowptr[i] = partial[blockIdx.x] + incl - v;
  if (i == NN - 1) rowptr[NN] = partial[blockIdx.x] + incl;
}

__global__ void fill_edges(const int* __restrict__ ei, const int* __restrict__ rowptr,
                           int* __restrict__ fillpos, int* __restrict__ col) {
  int e = blockIdx.x * 256 + threadIdx.x;
  if (e >= NE) return;
  int s = ei[e], d = ei[NE + e];
  int p = atomicAdd(&fillpos[d], 1);
  col[rowptr[d] + p] = s;
}

// ---------------------------------------------------------------- fragment pack (all matrices)
__global__ void prep_all(const float* __restrict__ gcn_W, const float* __restrict__ gat_W,
                         const float* __restrict__ hW1, const float* __restrict__ aW1,
                         const float* __restrict__ projW, unsigned short* __restrict__ wfrag,
                         unsigned short* __restrict__ nfrag, unsigned short* __restrict__ pfrag) {
  int m = blockIdx.y;
  int idx = blockIdx.x * 256 + threadIdx.x;  // 0..16383
  int j = idx & 7, lane = (idx >> 3) & 63, t = idx >> 9;
  int ct = t >> 2, ks = t & 3;
  int k = ks * 32 + ((lane >> 4) << 3) + j;
  int c = (ct << 4) + (lane & 15);
  if (m < 3) {
    wfrag[(size_t)m * 32768 + idx] = f2b(gcn_W[(size_t)m * 16384 + k * 128 + c]);
    wfrag[(size_t)m * 32768 + 16384 + idx] = f2b(gat_W[(size_t)m * 16384 + k * 128 + c]);
  } else if (m == 3) {
    float v = (c < 64) ? hW1[k * 64 + c] : aW1[k * 64 + (c - 64)];
    nfrag[idx] = f2b(v);
  } else {
    pfrag[idx] = f2b(projW[k * 128 + c]);
  }
}

// ---------------------------------------------------------------- A-fragment loaders
__device__ __forceinline__ void load_a_frags_f32(const float* __restrict__ xp, int lane,
                                                 bf16x8 a[4]) {
#pragma unroll
  for (int ks = 0; ks < 4; ++ks) {
    int k0 = ks * 32 + ((lane >> 4) << 3);
    float4 u = *(const float4*)&xp[k0];
    float4 v = *(const float4*)&xp[k0 + 4];
    bf16x8 t;
    t[0] = (short)f2b(u.x); t[1] = (short)f2b(u.y); t[2] = (short)f2b(u.z); t[3] = (short)f2b(u.w);
    t[4] = (short)f2b(v.x); t[5] = (short)f2b(v.y); t[6] = (short)f2b(v.z); t[7] = (short)f2b(v.w);
    a[ks] = t;
  }
}

__device__ __forceinline__ void load_a_frags_b16(const unsigned short* __restrict__ xp,
                                                 int lane, bf16x8 a[4]) {
#pragma unroll
  for (int ks = 0; ks < 4; ++ks) {
    int k0 = ks * 32 + ((lane >> 4) << 3);
    a[ks] = *(const bf16x8*)&xp[k0];
  }
}

// ---------------------------------------------------------------- projection MFMA GEMM -> bf16 xb
__global__ __launch_bounds__(256) void gemm_proj_mfma(
    const float* __restrict__ X, const unsigned short* __restrict__ F,
    const float* __restrict__ bias, unsigned short* __restrict__ XB, int nrows) {
  __shared__ unsigned short Ys[64 * 128];  // 16 KB
  int tid = threadIdx.x;
  int w = tid >> 6, lane = tid & 63;
  int row0 = blockIdx.x * 64;
  int row = row0 + w * 16 + (lane & 15);
  const float* xp = (row < nrows) ? &X[(size_t)row * 128] : &X[0];
  bf16x8 a[4];
  load_a_frags_f32(xp, lane, a);
  f32x4 acc[8];
#pragma unroll
  for (int ct = 0; ct < 8; ++ct) acc[ct] = (f32x4){0.f, 0.f, 0.f, 0.f};
#pragma unroll
  for (int ct = 0; ct < 8; ++ct) {
#pragma unroll
    for (int ks = 0; ks < 4; ++ks) {
      bf16x8 b = *(const bf16x8*)&F[((ct * 4 + ks) * 64 + lane) * 8];
      acc[ct] = __builtin_amdgcn_mfma_f32_16x16x32_bf16(a[ks], b, acc[ct], 0, 0, 0);
    }
  }
#pragma unroll
  for (int ct = 0; ct < 8; ++ct) {
    int c = (ct << 4) + (lane & 15);
    float bv = bias[c];
#pragma unroll
    for (int j = 0; j < 4; ++j) {
      int r = w * 16 + ((lane >> 4) << 2) + j;
      Ys[r * 128 + c] = f2b(acc[ct][j] + bv);
    }
  }
  __syncthreads();
  int nr = min(nrows - row0, 64);
  const uint4* ys4 = (const uint4*)Ys;
  uint4* y4 = (uint4*)(XB + (size_t)row0 * 128);
  for (int e = tid; e < nr * 16; e += 256) y4[e] = ys4[e];
}

// ---------------------------------------------------------------- dual MFMA GEMM -> G + fused GAT scores
// block 0 zeroes S1/S2 for the later graph_stats kernel.
__global__ __launch_bounds__(256) void gemm_dual_mfma(
    const unsigned short* __restrict__ XB, const unsigned short* __restrict__ F1,
    const unsigned short* __restrict__ F2, const float* __restrict__ asrc,
    const float* __restrict__ adst, const float* __restrict__ dis,
    unsigned short* __restrict__ G, float* __restrict__ a_s, float* __restrict__ a_d,
    float* __restrict__ S1z, int nrows) {
  if (blockIdx.x == 0) {
    for (int i = threadIdx.x; i < 2 * NG * 128; i += 256) S1z[i] = 0.f;
  }
  __shared__ unsigned short Gs[64 * 256];  // 32 KB
  int tid = threadIdx.x;
  int w = tid >> 6, lane = tid & 63;
  int row0 = blockIdx.x * 64;
  int row = row0 + w * 16 + (lane & 15);
  const unsigned short* xp = (row < nrows) ? &XB[(size_t)row * 128] : &XB[0];
  bf16x8 a[4];
  load_a_frags_b16(xp, lane, a);
  f32x4 acc1[8], acc2[8];
#pragma unroll
  for (int ct = 0; ct < 8; ++ct) {
    acc1[ct] = (f32x4){0.f, 0.f, 0.f, 0.f};
    acc2[ct] = (f32x4){0.f, 0.f, 0.f, 0.f};
  }
#pragma unroll
  for (int ct = 0; ct < 8; ++ct) {
#pragma unroll
    for (int ks = 0; ks < 4; ++ks) {
      int off = ((ct * 4 + ks) * 64 + lane) * 8;
      bf16x8 b1 = *(const bf16x8*)&F1[off];
      bf16x8 b2 = *(const bf16x8*)&F2[off];
      acc1[ct] = __builtin_amdgcn_mfma_f32_16x16x32_bf16(a[ks], b1, acc1[ct], 0, 0, 0);
      acc2[ct] = __builtin_amdgcn_mfma_f32_16x16x32_bf16(a[ks], b2, acc2[ct], 0, 0, 0);
    }
  }
  float dv[4];
#pragma unroll
  for (int j = 0; j < 4; ++j) {
    int gr = row0 + w * 16 + ((lane >> 4) << 2) + j;
    dv[j] = dis[gr < nrows ? gr : 0];
  }
#pragma unroll
  for (int ct = 0; ct < 8; ++ct) {
#pragma unroll
    for (int j = 0; j < 4; ++j) {
      int r = w * 16 + ((lane >> 4) << 2) + j;
      int c = (ct << 4) + (lane & 15);
      Gs[r * 256 + c] = f2b(acc1[ct][j] * dv[j]);
      Gs[r * 256 + 128 + c] = f2b(acc2[ct][j]);
    }
  }
  __syncthreads();
  int nr = min(nrows - row0, 64);
  const uint4* gs4 = (const uint4*)Gs;
  uint4* g4 = (uint4*)(G + (size_t)row0 * 256);
  for (int e = tid; e < nr * 32; e += 256) g4[e] = gs4[e];
  // fused attention scores from the LDS tile
  int f = 2 * lane;
  float as0 = asrc[f], as1 = asrc[f + 1];
  float ad0 = adst[f], ad1 = adst[f + 1];
  for (int i = 0; i < 16; ++i) {
    int r = w * 16 + i;
    int n = row0 + r;
    if (n >= nrows) break;
    ushort2 v = *(const ushort2*)&Gs[r * 256 + 128 + f];
    float x0 = b2f(v.x), x1 = b2f(v.y);
    float ps = x0 * as0 + x1 * as1;
    float pd = x0 * ad0 + x1 * ad1;
    ps += __shfl_xor(ps, 1); pd += __shfl_xor(pd, 1);
    ps += __shfl_xor(ps, 2); pd += __shfl_xor(pd, 2);
    ps += __shfl_xor(ps, 4); pd += __shfl_xor(pd, 4);
    ps += __shfl_xor(ps, 8); pd += __shfl_xor(pd, 8);
    if ((lane & 15) == 0) {
      int h = lane >> 4;
      a_s[n * 4 + h] = ps;
      a_d[n * 4 + h] = pd;
    }
  }
}

// ---------------------------------------------------------------- edge aggregation (edge-parallel) -> bf16 h
__device__ __forceinline__ float lrelu(float v) { return v > 0.f ? v : 0.2f * v; }

__global__ __launch_bounds__(256) void edge_aggregate_p(
    const unsigned short* __restrict__ G, const float* __restrict__ a_s,
    const float* __restrict__ a_d, const float* __restrict__ dis,
    const int* __restrict__ rowptr, const int* __restrict__ col,
    const float* __restrict__ gcn_b, const float* __restrict__ gat_b,
    unsigned short* __restrict__ hb) {
  int n = blockIdx.x * 4 + (threadIdx.x >> 6);
  int lane = threadIdx.x & 63;
  int es = lane >> 4, fl = lane & 15;
  int h = fl >> 2;
  int f8 = fl << 3;
  int p0 = rowptr[n], p1 = rowptr[n + 1];
  int cnt = p1 - p0 + 1;  // + self loop
  float adh = a_d[n * 4 + h];
  float dn = dis[n];
  float ag[8] = {0.f, 0.f, 0.f, 0.f, 0.f, 0.f, 0.f, 0.f};
  float aa[8] = {0.f, 0.f, 0.f, 0.f, 0.f, 0.f, 0.f, 0.f};
  float ssum = 0.f;
#define EDGE_ACC(eu, xv, hv)                                \
  do {                                                      \
    ag[0] += __uint_as_float((xv).x << 16);                 \
    ag[1] += __uint_as_float((xv).x & 0xffff0000u);         \
    ag[2] += __uint_as_float((xv).y << 16);                 \
    ag[3] += __uint_as_float((xv).y & 0xffff0000u);         \
    ag[4] += __uint_as_float((xv).z << 16);                 \
    ag[5] += __uint_as_float((xv).z & 0xffff0000u);         \
    ag[6] += __uint_as_float((xv).w << 16);                 \
    ag[7] += __uint_as_float((xv).w & 0xffff0000u);         \
    aa[0] += (eu)*__uint_as_float((hv).x << 16);            \
    aa[1] += (eu)*__uint_as_float((hv).x & 0xffff0000u);    \
    aa[2] += (eu)*__uint_as_float((hv).y << 16);            \
    aa[3] += (eu)*__uint_as_float((hv).y & 0xffff0000u);    \
    aa[4] += (eu)*__uint_as_float((hv).z << 16);            \
    aa[5] += (eu)*__uint_as_float((hv).z & 0xffff0000u);    \
    aa[6] += (eu)*__uint_as_float((hv).w << 16);            \
    aa[7] += (eu)*__uint_as_float((hv).w & 0xffff0000u);    \
  } while (0)
  int e = es;
  for (; e + 4 < cnt; e += 8) {
    int eB = e + 4;
    int srcA = (e < cnt - 1) ? col[p0 + e] : n;
    int srcB = (eB < cnt - 1) ? col[p0 + eB] : n;
    float euA = __expf(lrelu(a_s[srcA * 4 + h] + adh));
    float euB = __expf(lrelu(a_s[srcB * 4 + h] + adh));
    uint4 xvA = *(const uint4*)&G[(size_t)srcA * 256 + f8];
    uint4 hvA = *(const uint4*)&G[(size_t)srcA * 256 + 128 + f8];
    uint4 xvB = *(const uint4*)&G[(size_t)srcB * 256 + f8];
    uint4 hvB = *(const uint4*)&G[(size_t)srcB * 256 + 128 + f8];
    ssum += euA + euB;
    EDGE_ACC(euA, xvA, hvA);
    EDGE_ACC(euB, xvB, hvB);
  }
  for (; e < cnt; e += 4) {
    int src = (e < cnt - 1) ? col[p0 + e] : n;
    float eu = __expf(lrelu(a_s[src * 4 + h] + adh));
    uint4 xv = *(const uint4*)&G[(size_t)src * 256 + f8];
    uint4 hv = *(const uint4*)&G[(size_t)src * 256 + 128 + f8];
    ssum += eu;
    EDGE_ACC(eu, xv, hv);
  }
#undef EDGE_ACC
#pragma unroll
  for (int j = 0; j < 8; ++j) {
    ag[j] += __shfl_xor(ag[j], 16); ag[j] += __shfl_xor(ag[j], 32);
    aa[j] += __shfl_xor(aa[j], 16); aa[j] += __shfl_xor(aa[j], 32);
  }
  ssum += __shfl_xor(ssum, 16); ssum += __shfl_xor(ssum, 32);
  if (es == 0) {
    float rs = 1.f / ssum;
    float4 gb0 = *(const float4*)&gcn_b[f8];
    float4 gb1 = *(const float4*)&gcn_b[f8 + 4];
    float4 tb0 = *(const float4*)&gat_b[f8];
    float4 tb1 = *(const float4*)&gat_b[f8 + 4];
    float o[8];
    o[0] = ag[0] * dn + aa[0] * rs + gb0.x + tb0.x;
    o[1] = ag[1] * dn + aa[1] * rs + gb0.y + tb0.y;
    o[2] = ag[2] * dn + aa[2] * rs + gb0.z + tb0.z;
    o[3] = ag[3] * dn + aa[3] * rs + gb0.w + tb0.w;
    o[4] = ag[4] * dn + aa[4] * rs + gb1.x + tb1.x;
    o[5] = ag[5] * dn + aa[5] * rs + gb1.y + tb1.y;
    o[6] = ag[6] * dn + aa[6] * rs + gb1.z + tb1.z;
    o[7] = ag[7] * dn + aa[7] * rs + gb1.w + tb1.w;
    uint4 pk;
    pk.x = pack2(o[0], o[1]);
    pk.y = pack2(o[2], o[3]);
    pk.z = pack2(o[4], o[5]);
    pk.w = pack2(o[6], o[7]);
    *(uint4*)&hb[(size_t)n * 128 + f8] = pk;
  }
}

// ---------------------------------------------------------------- GraphNorm stats (bf16 h)
__global__ __launch_bounds__(128) void graph_stats_par(
    const unsigned short* __restrict__ hb, const int* __restrict__ batch,
    float* __restrict__ S1, float* __restrict__ S2) {
  int f = threadIdx.x;
  int n0 = blockIdx.x * 64;
  int n1 = min(n0 + 64, NN);
  int g = batch[n0];
  float s1 = 0.f, s2 = 0.f;
  for (int n = n0; n < n1; ++n) {
    int gn = batch[n];
    if (gn != g) {
      atomicAdd(&S1[g * 128 + f], s1);
      atomicAdd(&S2[g * 128 + f], s2);
      s1 = 0.f; s2 = 0.f; g = gn;
    }
    float v = b2f(hb[(size_t)n * 128 + f]);
    s1 += v; s2 += v * v;
  }
  atomicAdd(&S1[g * 128 + f], s1);
  atomicAdd(&S2[g * 128 + f], s2);
}

// ---------------------------------------------------------------- GraphNorm apply (bf16 h, bf16 x)
__global__ __launch_bounds__(256) void graph_norm(
    const unsigned short* __restrict__ hb, const int* __restrict__ batch,
    const int* __restrict__ gstart, const float* __restrict__ S1,
    const float* __restrict__ S2, const float* __restrict__ nw,
    const float* __restrict__ nb, const float* __restrict__ nms,
    unsigned short* __restrict__ xb, int layer) {
  int idx = blockIdx.x * 256 + threadIdx.x;  // 4 features per thread
  if (idx >= NN * 32) return;
  int n = idx >> 5, fq = (idx & 31) << 2;
  int g = batch[n];
  float c = fmaxf((float)(gstart[g + 1] - gstart[g]), 1.f);
  float rc = 1.f / c;
  float4 s1 = *(const float4*)&S1[g * 128 + fq];
  float4 s2 = *(const float4*)&S2[g * 128 + fq];
  float4 ms = *(const float4*)&nms[fq];
  float4 w = *(const float4*)&nw[fq];
  float4 b = *(const float4*)&nb[fq];
  ushort4 hv4 = *(const ushort4*)&hb[(size_t)n * 128 + fq];
  float4 hv;
  hv.x = b2f(hv4.x); hv.y = b2f(hv4.y); hv.z = b2f(hv4.z); hv.w = b2f(hv4.w);
  float4 o;
#define GN1(X)                                                           \
  {                                                                      \
    float mean = s1.X * rc;                                              \
    float var = s2.X * rc - mean * mean * ms.X * (2.f - ms.X);           \
    var = fmaxf(var, 0.f);                                               \
    float ot = (hv.X - ms.X * mean) * rsqrtf(var + 1e-5f);               \
    float t = w.X * ot + b.X;                                            \
    o.X = t > 0.f ? t : 0.f;                                             \
  }
  GN1(x) GN1(y) GN1(z) GN1(w)
#undef GN1
  ushort4* xp = (ushort4*)&xb[(size_t)n * 128 + fq];
  float4 xo = o;
  if (layer != 0) {
    ushort4 pv = *xp;
    xo.x += b2f(pv.x); xo.y += b2f(pv.y); xo.z += b2f(pv.z); xo.w += b2f(pv.w);
  }
  ushort4 bo;
  bo.x = f2b(xo.x); bo.y = f2b(xo.y); bo.z = f2b(xo.z); bo.w = f2b(xo.w);
  *xp = bo;
}

// ---------------------------------------------------------------- node MLPs (MFMA) + fused per-graph pooling
__global__ __launch_bounds__(256) void node_mlps_pool(
    const unsigned short* __restrict__ XB, const unsigned short* __restrict__ Fn,
    const float* __restrict__ hb1, const float* __restrict__ ab1,
    const float* __restrict__ hW2, const float* __restrict__ hb2,
    const float* __restrict__ aW2, const float* __restrict__ ab2,
    const int* __restrict__ batch, float* __restrict__ hub_feat,
    float* __restrict__ w_att, float* __restrict__ Sx, unsigned* __restrict__ Mx,
    float* __restrict__ WSx, float* __restrict__ Shub) {
  __shared__ float Hs[64 * 133];  // 34 KB
  __shared__ float Hf[64 * 4];
  __shared__ float Wa[64];
  int tid = threadIdx.x;
  int w = tid >> 6, lane = tid & 63;
  int row0 = blockIdx.x * 64;
  int row = row0 + w * 16 + (lane & 15);
  const unsigned short* xp = (row < NN) ? &XB[(size_t)row * 128] : &XB[0];
  bf16x8 a[4];
  load_a_frags_b16(xp, lane, a);
  f32x4 acc[8];
#pragma unroll
  for (int ct = 0; ct < 8; ++ct) acc[ct] = (f32x4){0.f, 0.f, 0.f, 0.f};
#pragma unroll
  for (int ct = 0; ct < 8; ++ct) {
#pragma unroll
    for (int ks = 0; ks < 4; ++ks) {
      bf16x8 b = *(const bf16x8*)&Fn[((ct * 4 + ks) * 64 + lane) * 8];
      acc[ct] = __builtin_amdgcn_mfma_f32_16x16x32_bf16(a[ks], b, acc[ct], 0, 0, 0);
    }
  }
#pragma unroll
  for (int ct = 0; ct < 8; ++ct) {
    int c = (ct << 4) + (lane & 15);
    float bias = (c < 64) ? hb1[c] : ab1[c - 64];
#pragma unroll
    for (int j = 0; j < 4; ++j) {
      int r = w * 16 + ((lane >> 4) << 2) + j;
      float v = acc[ct][j] + bias;
      Hs[r * 133 + c] = v > 0.f ? v : 0.f;
    }
  }
  __syncthreads();
  {
    int r = tid & 63, o = tid >> 6;
    int n = row0 + r;
    if (n < NN) {
      float d = hb2[o];
#pragma unroll 8
      for (int k = 0; k < 64; ++k) d += Hs[r * 133 + k] * hW2[k * 4 + o];
      hub_feat[n * 4 + o] = d;
      Hf[r * 4 + o] = d;
      if (tid < 64) {
        float d2 = ab2[0];
#pragma unroll 8
        for (int k = 0; k < 64; ++k) d2 += Hs[r * 133 + 64 + k] * aW2[k];
        w_att[n] = d2;
        Wa[r] = d2;
      }
    }
  }
  __syncthreads();
  // fused pooling over this block's 64 nodes (threads 0..127, f = tid)
  if (tid < 128) {
    int f = tid;
    int n0 = row0;
    int n1 = min(n0 + 64, NN);
    if (n0 < NN) {
      int g = batch[n0];
      float sx = 0.f, wx = 0.f, mx = 0.f, sh = 0.f;
      for (int n = n0; n < n1; ++n) {
        int gn = batch[n];
        if (gn != g) {
          atomicAdd(&Sx[g * 128 + f], sx);
          atomicAdd(&WSx[g * 128 + f], wx);
          atomicMax(&Mx[g * 128 + f], __float_as_uint(mx));
          if (f < 4) atomicAdd(&Shub[g * 4 + f], sh);
          sx = 0.f; wx = 0.f; mx = 0.f; sh = 0.f; g = gn;
        }
        float xv = b2f(XB[(size_t)n * 128 + f]);
        float ew = __expf(Wa[n - n0]);
        sx += xv;
        wx += ew * xv;
        mx = fmaxf(mx, xv);
        if (f < 4) sh += Hf[(n - n0) * 4 + f];
      }
      atomicAdd(&Sx[g * 128 + f], sx);
      atomicAdd(&WSx[g * 128 + f], wx);
      atomicMax(&Mx[g * 128 + f], __float_as_uint(mx));
      if (f < 4) atomicAdd(&Shub[g * 4 + f], sh);
    }
  }
}

// ---------------------------------------------------------------- global softmax denominator (atomic)
__global__ void reduce_sum1(const float* __restrict__ w, float* __restrict__ scal) {
  __shared__ float s[256];
  int t = threadIdx.x;
  float acc = 0.f;
  for (int i = blockIdx.x * 256 + t; i < NN; i += gridDim.x * 256) acc += __expf(w[i]);
  s[t] = acc;
  __syncthreads();
  for (int off = 128; off; off >>= 1) {
    if (t < off) s[t] += s[t + off];
    __syncthreads();
  }
  if (!t) atomicAdd(&scal[1], s[0]);
}

// ---------------------------------------------------------------- finalize: graph MLPs + outputs
__global__ __launch_bounds__(128) void finalize(
    const float* __restrict__ Sx, const float* __restrict__ Mx,
    const float* __restrict__ WSx, const float* __restrict__ Shub,
    const float* __restrict__ scal, const int* __restrict__ gstart,
    const int* __restrict__ cnt_src, const int* __restrict__ cnt_dst,
    const float* __restrict__ pW1, const float* __restrict__ pb1,
    const float* __restrict__ pW2, const float* __restrict__ pb2,
    const float* __restrict__ pW3, const float* __restrict__ pb3,
    const float* __restrict__ cW1, const float* __restrict__ cb1,
    const float* __restrict__ cW2, const float* __restrict__ cb2,
    const float* __restrict__ cW3, const float* __restrict__ cb3,
    float* __restrict__ out) {
  int g = blockIdx.x, t = threadIdx.x;
  __shared__ float pe[256], comb[140], buf1[128], buf2[64];
  __shared__ int snd[128];
  int s = gstart[g], e = gstart[g + 1];
  float c = fmaxf((float)(e - s), 1.f);
  int mdeg = 0;
  for (int n = s + t; n < e; n += 128) mdeg = max(mdeg, cnt_src[n] + cnt_dst[n]);
  snd[t] = mdeg;
  float* out_logits = out;                 // 128
  float* out_hub = out + 128;              // 64
  float* out_ge = out + 192;               // 8192
  float* out_hp = out + 192 + 8192;        // 256
  float* out_pf = out + 192 + 8192 + 256;  // 512
  float ge = WSx[g * 128 + t] / scal[1];
  out_ge[g * 128 + t] = ge;
  comb[t] = ge;
  pe[t] = Sx[g * 128 + t] / c;
  pe[128 + t] = Mx[g * 128 + t];
  if (t < 4) {
    float hp = Shub[g * 4 + t] / c;
    out_hp[g * 4 + t] = hp;
    comb[128 + t] = hp;
  }
  __syncthreads();
  for (int off = 64; off; off >>= 1) {
    if (t < off) snd[t] = max(snd[t], snd[t + off]);
    __syncthreads();
  }
  if (t == 0) out_hub[g] = (snd[0] > 0) ? 1.f : 0.f;
  // pattern MLP
  float v = pb1[t];
  for (int k = 0; k < 256; ++k) v += pe[k] * pW1[k * 128 + t];
  buf1[t] = v > 0.f ? v : 0.f;
  __syncthreads();
  if (t < 64) {
    float v2 = pb2[t];
    for (int k = 0; k < 128; ++k) v2 += buf1[k] * pW2[k * 64 + t];
    buf2[t] = v2 > 0.f ? v2 : 0.f;
  }
  __syncthreads();
  if (t < 8) {
    float v3 = pb3[t];
    for (int k = 0; k < 64; ++k) v3 += buf2[k] * pW3[k * 8 + t];
    out_pf[g * 8 + t] = v3;
    comb[132 + t] = v3;
  }
  __syncthreads();
  // classifier
  float u = cb1[t];
  for (int k = 0; k < 140; ++k) u += comb[k] * cW1[k * 128 + t];
  buf1[t] = u > 0.f ? u : 0.f;
  __syncthreads();
  if (t < 64) {
    float u2 = cb2[t];
    for (int k = 0; k < 128; ++k) u2 += buf1[k] * cW2[k * 64 + t];
    buf2[t] = u2 > 0.f ? u2 : 0.f;
  }
  __syncthreads();
  if (t < 2) {
    float u3 = cb3[t];
    for (int k = 0; k < 64; ++k) u3 += buf2[k] * cW3[k * 2 + t];
    out_logits[g * 2 + t] = u3;
  }
}

// ---------------------------------------------------------------- launch
extern "C" void kernel_launch(void* const* d_in, const int* in_sizes, int n_in,
                              void* d_out, int out_size, void* d_ws, size_t ws_size,
                              hipStream_t stream) {
  const float* x_in = (const float*)d_in[0];
  const int* ei = (const int*)d_in[1];
  const int* batch = (const int*)d_in[2];
  const float* proj_W = (const float*)d_in[3];
  const float* proj_b = (const float*)d_in[4];
  const float* gcn_W = (const float*)d_in[5];
  const float* gcn_b = (const float*)d_in[6];
  const float* gat_W = (const float*)d_in[7];
  const float* gat_as = (const float*)d_in[8];
  const float* gat_ad = (const float*)d_in[9];
  const float* gat_b = (const float*)d_in[10];
  const float* norm_w = (const float*)d_in[11];
  const float* norm_b = (const float*)d_in[12];
  const float* norm_ms = (const float*)d_in[13];
  const float* hub_W1 = (const float*)d_in[14];
  const float* hub_b1 = (const float*)d_in[15];
  const float* hub_W2 = (const float*)d_in[16];
  const float* hub_b2 = (const float*)d_in[17];
  const float* att_W1 = (const float*)d_in[18];
  const float* att_b1 = (const float*)d_in[19];
  const float* att_W2 = (const float*)d_in[20];
  const float* att_b2 = (const float*)d_in[21];
  const float* pat_W1 = (const float*)d_in[22];
  const float* pat_b1 = (const float*)d_in[23];
  const float* pat_W2 = (const float*)d_in[24];
  const float* pat_b2 = (const float*)d_in[25];
  const float* pat_W3 = (const float*)d_in[26];
  const float* pat_b3 = (const float*)d_in[27];
  const float* cls_W1 = (const float*)d_in[28];
  const float* cls_b1 = (const float*)d_in[29];
  const float* cls_W2 = (const float*)d_in[30];
  const float* cls_b2 = (const float*)d_in[31];
  const float* cls_W3 = (const float*)d_in[32];
  const float* cls_b3 = (const float*)d_in[33];
  float* out = (float*)d_out;

  char* ws = (char*)d_ws;
  auto fbuf = [&](size_t n) { float* p = (float*)ws; ws += ((n * 4 + 255) / 256) * 256; return p; };
  auto ibuf = [&](size_t n) { int* p = (int*)ws; ws += ((n * 4 + 255) / 256) * 256; return p; };

  // ---- zeroed-at-launch region (one memset): cnt_dst|cnt_src|fillpos + pool accums + scal
  int* zero0 = ibuf(3 * NN);
  int* cnt_dst = zero0;
  int* cnt_src = zero0 + NN;
  int* fillpos = zero0 + 2 * NN;
  float* Sx = fbuf(NG * 128);
  float* Mx = fbuf(NG * 128);
  float* WSx = fbuf(NG * 128);
  float* Shub = fbuf(NG * 4);
  float* scal = fbuf(4);
  size_t zbytes = (char*)ws - (char*)zero0;

  unsigned short* xb = (unsigned short*)fbuf((size_t)NN * 64);     // NN*128 bf16
  unsigned short* gath = (unsigned short*)fbuf((size_t)NN * 128);  // NN*256 bf16
  unsigned short* hbuf = (unsigned short*)fbuf((size_t)NN * 64);   // NN*128 bf16
  unsigned short* wfrag = (unsigned short*)fbuf(3 * 32768 / 2);
  unsigned short* nfrag = (unsigned short*)fbuf(16384 / 2);
  unsigned short* pfrag = (unsigned short*)fbuf(16384 / 2);
  float* a_s = fbuf((size_t)NN * 4);
  float* a_d = fbuf((size_t)NN * 4);
  float* dis = fbuf(NN);
  float* w_att = fbuf(NN);
  float* hub_feat = fbuf((size_t)NN * 4);
  float* S1 = fbuf(NG * 128);  // S1|S2 contiguous (zeroed by gemm_dual block 0)
  float* S2 = fbuf(NG * 128);
  int* rowptr = ibuf(NN + 1);
  int* col = ibuf(NE);
  int* partial = ibuf(256);
  int* gstart = ibuf(NG + 1);

  const int NB = (NN + 255) / 256;   // 196
  const int GM = (NN + 63) / 64;     // 782 (mfma gemm / node chunks)

  // --- CSR + degrees + graph bounds + weight packing
  hipMemsetAsync(zero0, 0, zbytes, stream);
  count_edges<<<NE / 256, 256, 0, stream>>>(ei, cnt_dst, cnt_src);
  scanA_dis<<<NB, 256, 0, stream>>>(cnt_dst, partial, dis);
  scanB_bounds<<<1, 128, 0, stream>>>(partial, NB, batch, gstart);
  scanC<<<NB, 256, 0, stream>>>(cnt_dst, partial, rowptr);
  fill_edges<<<NE / 256, 256, 0, stream>>>(ei, rowptr, fillpos, col);
  prep_all<<<dim3(64, 5), 256, 0, stream>>>(gcn_W, gat_W, hub_W1, att_W1, proj_W,
                                            wfrag, nfrag, pfrag);

  // --- projection (MFMA, bf16 out)
  gemm_proj_mfma<<<GM, 256, 0, stream>>>(x_in, pfrag, proj_b, xb, NN);

  // --- layers
  for (int l = 0; l < 3; ++l) {
    gemm_dual_mfma<<<GM, 256, 0, stream>>>(xb, wfrag + (size_t)l * 32768,
                                           wfrag + (size_t)l * 32768 + 16384,
                                           gat_as + l * 128, gat_ad + l * 128, dis,
                                           gath, a_s, a_d, S1, NN);
    edge_aggregate_p<<<NN / 4, 256, 0, stream>>>(gath, a_s, a_d, dis, rowptr, col,
                                                 gcn_b + l * 128, gat_b + l * 128, hbuf);
    graph_stats_par<<<GM, 128, 0, stream>>>(hbuf, batch, S1, S2);
    graph_norm<<<(NN * 32 + 255) / 256, 256, 0, stream>>>(hbuf, batch, gstart, S1, S2,
                                                          norm_w + l * 128, norm_b + l * 128,
                                                          norm_ms + l * 128, xb, l);
  }

  // --- node MLPs + fused per-graph pooling
  node_mlps_pool<<<GM, 256, 0, stream>>>(xb, nfrag, hub_b1, att_b1, hub_W2, hub_b2,
                                         att_W2, att_b2, batch, hub_feat, w_att,
                                         Sx, (unsigned*)Mx, WSx, Shub);

  // --- global softmax denominator
  reduce_sum1<<<256, 256, 0, stream>>>(w_att, scal);

  // --- finalize: graph-level MLPs + all outputs
  finalize<<<NG, 128, 0, stream>>>(Sx, Mx, WSx, Shub, scal, gstart, cnt_src, cnt_dst,
                                   pat_W1, pat_b1, pat_W2, pat_b2, pat_W3, pat_b3,
                                   cls_W1, cls_b1, cls_W2, cls_b2, cls_W3, cls_b3, out);
}